// Round 10
// baseline (2906.293 us; speedup 1.0000x reference)
//
#include <hip/hip_runtime.h>
#include <hip/hip_bf16.h>

typedef __bf16 bf16x8 __attribute__((ext_vector_type(8)));
typedef float  f32x4  __attribute__((ext_vector_type(4)));
typedef unsigned short u16;

#define DEVI __device__ __forceinline__
#define MFMA __builtin_amdgcn_mfma_f32_16x16x32_bf16

DEVI u16 f2bf(float f){
  unsigned u = __builtin_bit_cast(unsigned, f);
  u += 0x7fffu + ((u >> 16) & 1u);
  return (u16)(u >> 16);
}
DEVI float bf2f(u16 h){
  unsigned u = ((unsigned)h) << 16;
  return __builtin_bit_cast(float, u);
}

// ---- ws layout (bytes); bf16 MFMA B-fragments, identity column order ----
enum : int {
  OFF_IHF = 0,                       // Wih_f: (128,768)  KT=4
  OFF_HHF = 196608,                  // Whh_f: (256,768)  KT=8
  OFF_IHB = 589824,                  // Wih_b: (128,768)  KT=4
  OFF_IHD = 786432,                  // Wih_d: (128,768)  KT=4
  OFF_HHD = 983040,                  // Whh_d: (256,768)  KT=8
  OFF_ENC = 1376256,                 // W_enc: (512,128)  KT=16
  OFF_Z2H = 1507328,                 // W_z2h: (64,256)   KT=2
  OFF_H2I = 1540096,                 // W_h2i: (256,64)   KT=8
  OFF_DEC = 1572864,                 // W_dec: (256,32)   KT=8
  OFF_EE  = 1589248,                 // W_ee : (32,128)   KT=1
  OFF_ED  = 1597440,                 // W_ed : (32,64)    KT=1 (unused by main)
  OFF_DE  = 1601536,                 // Wde = Wdec@Wed: (256,64) KT=8
  OFF_BDE = 1634304,                 // bde = bdec@Wed + bed: 64 f32
  WS_TOTAL = 1634560
};

DEVI void packseg(const float* __restrict__ W, u16* __restrict__ dst, int li, int N, int KT){
  int j = li & 7, l = (li >> 3) & 63, f = li >> 9;
  int kt = f % KT, ntg = f / KT;
  int k = kt * 32 + ((l >> 4) << 3) + j;
  int col = (ntg << 4) + (l & 15);
  dst[li] = f2bf(W[k * N + col]);
}

__global__ void pack_all(const float* Wihf, const float* Whhf, const float* Wihb,
                         const float* Wihd, const float* Whhd, const float* Wenc,
                         const float* Wz2h, const float* Wh2i, const float* Wdec,
                         const float* Wee,  const float* Wed,
                         const float* bed,  const float* bdec, char* ws)
{
  int idx = blockIdx.x * 256 + threadIdx.x;
  if (idx < 98304) { packseg(Wihf, (u16*)(ws+OFF_IHF), idx, 768, 4); return; } idx -= 98304;
  if (idx < 196608){ packseg(Whhf, (u16*)(ws+OFF_HHF), idx, 768, 8); return; } idx -= 196608;
  if (idx < 98304) { packseg(Wihb, (u16*)(ws+OFF_IHB), idx, 768, 4); return; } idx -= 98304;
  if (idx < 98304) { packseg(Wihd, (u16*)(ws+OFF_IHD), idx, 768, 4); return; } idx -= 98304;
  if (idx < 196608){ packseg(Whhd, (u16*)(ws+OFF_HHD), idx, 768, 8); return; } idx -= 196608;
  if (idx < 65536) { packseg(Wenc, (u16*)(ws+OFF_ENC), idx, 128, 16); return; } idx -= 65536;
  if (idx < 16384) { packseg(Wz2h, (u16*)(ws+OFF_Z2H), idx, 256, 2); return; } idx -= 16384;
  if (idx < 16384) { packseg(Wh2i, (u16*)(ws+OFF_H2I), idx, 64, 8); return; } idx -= 16384;
  if (idx < 8192)  { packseg(Wdec, (u16*)(ws+OFF_DEC), idx, 32, 8); return; } idx -= 8192;
  if (idx < 4096)  { packseg(Wee,  (u16*)(ws+OFF_EE),  idx, 128, 1); return; } idx -= 4096;
  if (idx < 2048)  { packseg(Wed,  (u16*)(ws+OFF_ED),  idx, 64, 1); return; } idx -= 2048;
  if (idx < 16384){
    int j = idx & 7, l = (idx >> 3) & 63, f = idx >> 9;
    int kt = f & 7, ntg = f >> 3;
    int k = kt * 32 + ((l >> 4) << 3) + j;
    int col = (ntg << 4) + (l & 15);
    float acc = 0.f;
    for (int m = 0; m < 32; ++m) acc += Wdec[k*32 + m] * Wed[m*64 + col];
    ((u16*)(ws+OFF_DE))[idx] = f2bf(acc);
    return;
  } idx -= 16384;
  if (idx < 64){
    float acc = bed[idx];
    for (int m = 0; m < 32; ++m) acc += bdec[m] * Wed[m*64 + idx];
    ((float*)(ws+OFF_BDE))[idx] = acc;
  }
}

// ---- LDS geometry ----
enum : int { RB_A1 = 272, RB_A2 = 528, RB_X = 80 };

DEVI bf16x8 ldF(const char* buf, int row, int kElem, int rowB){
  return *(const bf16x8*)(buf + row * rowB + kElem * 2);
}
DEVI void stBf(char* buf, int row, int col, int rowB, float v){
  *(u16*)(buf + row * rowB + col * 2) = f2bf(v);
}
DEVI float ldBf1(const char* buf, int row, int col, int rowB){
  return bf2f(*(const u16*)(buf + row * rowB + col * 2));
}
DEVI bf16x8 gfrag(const u16* P, int ntg, int KT, int kt, int l){
  return *(const bf16x8*)(P + ((size_t)(ntg * KT + kt) * 64 + l) * 8);
}

// G12T: [1024 cols][16 samples bf16], 32 B rows, XOR-swizzled (bijective)
DEVI int gaddr(int col, int boff){
  int a = col * 32 + boff;
  return a ^ (((col >> 2) & 7) << 4);
}
DEVI void stG(char* g, int col, int g4, const f32x4& a){
  uint2 v;
  v.x = (unsigned)f2bf(a[0]) | ((unsigned)f2bf(a[1]) << 16);
  v.y = (unsigned)f2bf(a[2]) | ((unsigned)f2bf(a[3]) << 16);
  *(uint2*)(g + gaddr(col, g4 * 8)) = v;
}
DEVI void ldG4(const char* g, int col, int sq, float o[4]){
  uint2 v = *(const uint2*)(g + gaddr(col, sq * 8));
  o[0] = bf2f((u16)(v.x & 0xffffu)); o[1] = bf2f((u16)(v.x >> 16));
  o[2] = bf2f((u16)(v.y & 0xffffu)); o[3] = bf2f((u16)(v.y >> 16));
}

DEVI float sigm(float x){ return 1.0f / (1.0f + __expf(-x)); }
DEVI float tanh_f(float x){ return 1.0f - 2.0f / (1.0f + __expf(2.0f * x)); }

DEVI void stage_x(const float* __restrict__ xg, int s0, int t, char* Xb, int tid){
  if (tid < 256){
    int s = tid >> 4, d0 = (tid & 15) * 2;
    float2 v = *(const float2*)(xg + (size_t)(s0 + s) * 3200 + t * 32 + d0);
    unsigned pk = (unsigned)f2bf(v.x) | ((unsigned)f2bf(v.y) << 16);
    *(unsigned*)(Xb + s * RB_X + d0 * 2) = pk;
  }
}

// 128 blocks x 1024 threads (16 waves), M=16 samples/block, 1 block/CU
// (LDS ~86 KB forces it) => 4 waves/SIMD at 128 VGPR. Pure weight streaming:
// wave w owns gate groups {w, w+16, w+32, w+48}; 36 KB/wave/step from L2.
__global__ __launch_bounds__(1024, 1) void vae_main(
    const float* __restrict__ x, const float* __restrict__ eps,
    const float* __restrict__ b_ee,
    const float* __restrict__ bih_f, const float* __restrict__ bhh_f,
    const float* __restrict__ bih_b, const float* __restrict__ bhh_b,
    const float* __restrict__ bih_d, const float* __restrict__ bhh_d,
    const float* __restrict__ b_enc, const float* __restrict__ b_z2h,
    const float* __restrict__ b_h2i, const float* __restrict__ b_ed,
    const float* __restrict__ b_dec,
    const char* __restrict__ ws, float* __restrict__ out)
{
  __shared__ __align__(16) char G12T[1024 * 32];    // 32768, swizzled
  __shared__ __align__(16) char A1[2][16 * RB_A1];  // 8704
  __shared__ __align__(16) char A2s[16 * RB_A2];    // 8448 (h, 256 cols bf16)
  __shared__ __align__(16) char HBs[16 * RB_A2];    // 8448 (h_bwd)
  __shared__ __align__(16) char X0b[2][16 * RB_X];  // 2560
  __shared__ float ST[16 * 132];                    // 8448
  __shared__ char PAD[16384];                       // occupancy limiter: 1 block/CU

  const int tid = threadIdx.x;
  const int l = tid & 63;
  const int w = tid >> 6;       // wave 0..15
  const int c = l & 15;
  const int g4 = l >> 4;
  const int s0 = blockIdx.x * 16;
  const int u_ = tid & 255;     // hidden unit (combine)
  const int sq = tid >> 8;      // sample quarter 0..3 (4 samples each)

  if (tid == 0) PAD[0] = 1;     // keep PAD allocated

  const u16* PIHF = (const u16*)(ws + OFF_IHF);
  const u16* PHHF = (const u16*)(ws + OFF_HHF);
  const u16* PIHB = (const u16*)(ws + OFF_IHB);
  const u16* PIHD = (const u16*)(ws + OFF_IHD);
  const u16* PHHD = (const u16*)(ws + OFF_HHD);
  const u16* PENC = (const u16*)(ws + OFF_ENC);
  const u16* PZ2H = (const u16*)(ws + OFF_Z2H);
  const u16* PH2I = (const u16*)(ws + OFF_H2I);
  const u16* PDEC = (const u16*)(ws + OFF_DEC);
  const u16* PEE  = (const u16*)(ws + OFF_EE);
  const u16* PDE  = (const u16*)(ws + OFF_DE);

  const f32x4 zf = {0.f, 0.f, 0.f, 0.f};

  // combine biases (encoder set now; decoder set loaded later)
  float brX = bih_f[u_] + bhh_f[u_];
  float bzX = bih_f[256 + u_] + bhh_f[256 + u_];
  float binX = bih_f[512 + u_], bhnX = bhh_f[512 + u_];
  const float beer = b_ee[16 * (w & 7) + c];
  const bf16x8 bEE = gfrag(PEE, w & 7, 1, 0, l);

  float hreg[4];
  #pragma unroll
  for (int i = 0; i < 4; ++i) hreg[i] = 0.f;

  // ---------------- prologue ----------------
  stage_x(x, s0, 0, X0b[0], tid);
  for (int i = tid; i < 16 * RB_A2 / 4; i += 1024) ((unsigned*)A2s)[i] = 0u;  // h0 = 0
  __syncthreads();
  if (w < 8){
    bf16x8 a = ldF(X0b[0], c, g4 * 8, RB_X);
    f32x4 xa = MFMA(a, bEE, zf, 0, 0, 0);
    #pragma unroll
    for (int q = 0; q < 4; ++q)
      stBf(A1[0], g4 * 4 + q, 16 * w + c, RB_A1, fmaxf(xa[q] + beer, 0.f));
  }
  stage_x(x, s0, 1, X0b[1], tid);
  __syncthreads();

  // ---------------- encoder: 100 steps ----------------
  for (int t = 0; t < 100; ++t){
    bf16x8 a1f[4], a2f[8];
    #pragma unroll
    for (int kt = 0; kt < 4; ++kt) a1f[kt] = ldF(A1[t & 1], c, kt * 32 + g4 * 8, RB_A1);
    #pragma unroll
    for (int kt = 0; kt < 8; ++kt) a2f[kt] = ldF(A2s, c, kt * 32 + g4 * 8, RB_A2);

    f32x4 acc;
    // G = w : r (ih + hh)
    acc = zf;
    #pragma unroll
    for (int kt = 0; kt < 4; ++kt) acc = MFMA(a1f[kt], gfrag(PIHF, w, 4, kt, l), acc, 0, 0, 0);
    #pragma unroll
    for (int kt = 0; kt < 8; ++kt) acc = MFMA(a2f[kt], gfrag(PHHF, w, 8, kt, l), acc, 0, 0, 0);
    stG(G12T, 16 * w + c, g4, acc);
    // G = w+16 : z (ih + hh)
    acc = zf;
    #pragma unroll
    for (int kt = 0; kt < 4; ++kt) acc = MFMA(a1f[kt], gfrag(PIHF, w + 16, 4, kt, l), acc, 0, 0, 0);
    #pragma unroll
    for (int kt = 0; kt < 8; ++kt) acc = MFMA(a2f[kt], gfrag(PHHF, w + 16, 8, kt, l), acc, 0, 0, 0);
    stG(G12T, 16 * (w + 16) + c, g4, acc);
    // G = w+32 : in (ih only)
    acc = zf;
    #pragma unroll
    for (int kt = 0; kt < 4; ++kt) acc = MFMA(a1f[kt], gfrag(PIHF, w + 32, 4, kt, l), acc, 0, 0, 0);
    stG(G12T, 16 * (w + 32) + c, g4, acc);
    // G = w+48 : hn (hh only, hh-ntg = w+32)
    acc = zf;
    #pragma unroll
    for (int kt = 0; kt < 8; ++kt) acc = MFMA(a2f[kt], gfrag(PHHF, w + 32, 8, kt, l), acc, 0, 0, 0);
    stG(G12T, 16 * (w + 48) + c, g4, acc);

    if (t < 99 && w < 8){
      bf16x8 a = ldF(X0b[(t + 1) & 1], c, g4 * 8, RB_X);
      f32x4 xa = MFMA(a, bEE, zf, 0, 0, 0);
      #pragma unroll
      for (int q = 0; q < 4; ++q)
        stBf(A1[(t + 1) & 1], g4 * 4 + q, 16 * w + c, RB_A1, fmaxf(xa[q] + beer, 0.f));
    }
    if (t < 98) stage_x(x, s0, t + 2, X0b[t & 1], tid);
    __syncthreads();

    { // combine: thread owns (unit u_, 4 samples)
      float gr[4], gz[4], gi[4], gh[4];
      ldG4(G12T, u_,        sq, gr);
      ldG4(G12T, 256 + u_,  sq, gz);
      ldG4(G12T, 512 + u_,  sq, gi);
      ldG4(G12T, 768 + u_,  sq, gh);
      #pragma unroll
      for (int i = 0; i < 4; ++i){
        float r  = sigm(gr[i] + brX);
        float zz = sigm(gz[i] + bzX);
        float n  = tanh_f(gi[i] + binX + r * (gh[i] + bhnX));
        float h  = (1.f - zz) * n + zz * hreg[i];
        hreg[i] = h;
        stBf(A2s, sq * 4 + i, u_, RB_A2, h);
      }
    }
    __syncthreads();
  }

  // ---------------- backward cell (h0=0), gi from xe_99 in A1[1] ----------------
  {
    bf16x8 a1f[4];
    #pragma unroll
    for (int kt = 0; kt < 4; ++kt) a1f[kt] = ldF(A1[1], c, kt * 32 + g4 * 8, RB_A1);
    #pragma unroll
    for (int j = 0; j < 3; ++j){
      const int G = w + 16 * j;   // 0..47
      f32x4 acc = zf;
      #pragma unroll
      for (int kt = 0; kt < 4; ++kt) acc = MFMA(a1f[kt], gfrag(PIHB, G, 4, kt, l), acc, 0, 0, 0);
      stG(G12T, 16 * G + c, g4, acc);
    }
  }
  __syncthreads();
  { // backward combine -> HBs
    const float brb = bih_b[u_] + bhh_b[u_];
    const float bzb = bih_b[256 + u_] + bhh_b[256 + u_];
    const float binb = bih_b[512 + u_], bhnb = bhh_b[512 + u_];
    float gr[4], gz[4], gi[4];
    ldG4(G12T, u_,       sq, gr);
    ldG4(G12T, 256 + u_, sq, gz);
    ldG4(G12T, 512 + u_, sq, gi);
    #pragma unroll
    for (int i = 0; i < 4; ++i){
      float r  = sigm(gr[i] + brb);
      float zz = sigm(gz[i] + bzb);
      float n  = tanh_f(gi[i] + binb + r * bhnb);   // h0=0 => hn = bhh_b
      stBf(HBs, sq * 4 + i, u_, RB_A2, (1.f - zz) * n);
    }
  }
  __syncthreads();

  // ---------------- stats = [h_fwd | h_bwd] @ W_enc + b_enc ----------------
  if (w < 8){
    f32x4 sa = zf;
    #pragma unroll
    for (int kt = 0; kt < 8; ++kt)
      sa = MFMA(ldF(A2s, c, kt * 32 + g4 * 8, RB_A2), gfrag(PENC, w, 16, kt, l), sa, 0, 0, 0);
    #pragma unroll
    for (int kt = 8; kt < 16; ++kt)
      sa = MFMA(ldF(HBs, c, (kt - 8) * 32 + g4 * 8, RB_A2), gfrag(PENC, w, 16, kt, l), sa, 0, 0, 0);
    const float be = b_enc[16 * w + c];
    #pragma unroll
    for (int q = 0; q < 4; ++q)
      ST[(g4 * 4 + q) * 132 + 16 * w + c] = sa[q] + be;
  }
  __syncthreads();

  // ---------------- z; write mu/logvar (f32) ----------------
  {
    const int s = tid >> 6, j = tid & 63;
    float mu = ST[s * 132 + j], lv = ST[s * 132 + 64 + j];
    out[6553600u + (size_t)(s0 + s) * 64 + j] = mu;
    out[6684672u + (size_t)(s0 + s) * 64 + j] = lv;
    float zv = mu + __expf(0.5f * lv) * eps[(size_t)(s0 + s) * 64 + j];
    stBf(A1[0], s, j, RB_A1, zv);
  }
  __syncthreads();

  // ---------------- h_dec0 = relu(z @ W_z2h + b_z2h) -> A2s; dec biases ----------------
  {
    f32x4 da = zf;
    #pragma unroll
    for (int kt = 0; kt < 2; ++kt)
      da = MFMA(ldF(A1[0], c, kt * 32 + g4 * 8, RB_A1), gfrag(PZ2H, w, 2, kt, l), da, 0, 0, 0);
    const float bz = b_z2h[16 * w + c];
    #pragma unroll
    for (int q = 0; q < 4; ++q)
      stBf(A2s, g4 * 4 + q, 16 * w + c, RB_A2, fmaxf(da[q] + bz, 0.f));
    brX = bih_d[u_] + bhh_d[u_];
    bzX = bih_d[256 + u_] + bhh_d[256 + u_];
    binX = bih_d[512 + u_]; bhnX = bhh_d[512 + u_];
  }
  __syncthreads();

  // ---------------- hd preload, hid0 (w<4), cur0 ----------------
  #pragma unroll
  for (int i = 0; i < 4; ++i) hreg[i] = ldBf1(A2s, sq * 4 + i, u_, RB_A2);
  if (w < 4){
    f32x4 ha = zf;
    #pragma unroll
    for (int kt = 0; kt < 8; ++kt)
      ha = MFMA(ldF(A2s, c, kt * 32 + g4 * 8, RB_A2), gfrag(PH2I, w, 8, kt, l), ha, 0, 0, 0);
    const float bh = b_h2i[16 * w + c];
    #pragma unroll
    for (int q = 0; q < 4; ++q)
      stBf(A1[0], g4 * 4 + q, 64 + 16 * w + c, RB_A1, fmaxf(ha[q] + bh, 0.f));
  }
  {
    const int s = tid >> 6, j = tid & 63;
    stBf(A1[0], s, j, RB_A1, fmaxf(b_ed[j], 0.f));
  }
  __syncthreads();

  const float bh2ir = (w < 4) ? b_h2i[16 * w + c] : 0.f;
  const float bder  = (w >= 4 && w < 8) ? ((const float*)(ws + OFF_BDE))[16 * (w - 4) + c] : 0.f;
  const float bdecr = (w >= 8 && w < 10) ? b_dec[16 * (w - 8) + c] : 0.f;

  // ---------------- decoder: 100 steps ----------------
  for (int t = 0; t < 100; ++t){
    bf16x8 a1f[4], a2f[8];
    #pragma unroll
    for (int kt = 0; kt < 4; ++kt) a1f[kt] = ldF(A1[0], c, kt * 32 + g4 * 8, RB_A1);
    #pragma unroll
    for (int kt = 0; kt < 8; ++kt) a2f[kt] = ldF(A2s, c, kt * 32 + g4 * 8, RB_A2);

    f32x4 acc;
    acc = zf;
    #pragma unroll
    for (int kt = 0; kt < 4; ++kt) acc = MFMA(a1f[kt], gfrag(PIHD, w, 4, kt, l), acc, 0, 0, 0);
    #pragma unroll
    for (int kt = 0; kt < 8; ++kt) acc = MFMA(a2f[kt], gfrag(PHHD, w, 8, kt, l), acc, 0, 0, 0);
    stG(G12T, 16 * w + c, g4, acc);
    acc = zf;
    #pragma unroll
    for (int kt = 0; kt < 4; ++kt) acc = MFMA(a1f[kt], gfrag(PIHD, w + 16, 4, kt, l), acc, 0, 0, 0);
    #pragma unroll
    for (int kt = 0; kt < 8; ++kt) acc = MFMA(a2f[kt], gfrag(PHHD, w + 16, 8, kt, l), acc, 0, 0, 0);
    stG(G12T, 16 * (w + 16) + c, g4, acc);
    acc = zf;
    #pragma unroll
    for (int kt = 0; kt < 4; ++kt) acc = MFMA(a1f[kt], gfrag(PIHD, w + 32, 4, kt, l), acc, 0, 0, 0);
    stG(G12T, 16 * (w + 32) + c, g4, acc);
    acc = zf;
    #pragma unroll
    for (int kt = 0; kt < 8; ++kt) acc = MFMA(a2f[kt], gfrag(PHHD, w + 32, 8, kt, l), acc, 0, 0, 0);
    stG(G12T, 16 * (w + 48) + c, g4, acc);
    __syncthreads();

    { // combine -> h2
      float gr[4], gz[4], gi[4], gh[4];
      ldG4(G12T, u_,        sq, gr);
      ldG4(G12T, 256 + u_,  sq, gz);
      ldG4(G12T, 512 + u_,  sq, gi);
      ldG4(G12T, 768 + u_,  sq, gh);
      #pragma unroll
      for (int i = 0; i < 4; ++i){
        float r  = sigm(gr[i] + brX);
        float zz = sigm(gz[i] + bzX);
        float n  = tanh_f(gi[i] + binX + r * (gh[i] + bhnX));
        float h  = (1.f - zz) * n + zz * hreg[i];
        hreg[i] = h;
        stBf(A2s, sq * 4 + i, u_, RB_A2, h);
      }
    }
    __syncthreads();

    // heads: w0-3 h2i -> A1 hi; w4-7 fused cur (Wde) -> A1 lo; w8-9 x_cur -> out
    if (w < 10){
      bf16x8 af[8];
      #pragma unroll
      for (int kt = 0; kt < 8; ++kt) af[kt] = ldF(A2s, c, kt * 32 + g4 * 8, RB_A2);
      f32x4 hv = zf;
      if (w < 4){
        #pragma unroll
        for (int kt = 0; kt < 8; ++kt) hv = MFMA(af[kt], gfrag(PH2I, w, 8, kt, l), hv, 0, 0, 0);
        #pragma unroll
        for (int q = 0; q < 4; ++q)
          stBf(A1[0], g4 * 4 + q, 64 + 16 * w + c, RB_A1, fmaxf(hv[q] + bh2ir, 0.f));
      } else if (w < 8){
        #pragma unroll
        for (int kt = 0; kt < 8; ++kt) hv = MFMA(af[kt], gfrag(PDE, w - 4, 8, kt, l), hv, 0, 0, 0);
        #pragma unroll
        for (int q = 0; q < 4; ++q)
          stBf(A1[0], g4 * 4 + q, 16 * (w - 4) + c, RB_A1, fmaxf(hv[q] + bder, 0.f));
      } else {
        #pragma unroll
        for (int kt = 0; kt < 8; ++kt) hv = MFMA(af[kt], gfrag(PDEC, w - 8, 8, kt, l), hv, 0, 0, 0);
        #pragma unroll
        for (int q = 0; q < 4; ++q)
          out[(size_t)(s0 + g4 * 4 + q) * 3200 + t * 32 + 16 * (w - 8) + c] = hv[q] + bdecr;
      }
    }
    __syncthreads();
  }
}

extern "C" void kernel_launch(void* const* d_in, const int* in_sizes, int n_in,
                              void* d_out, int out_size, void* d_ws, size_t ws_size,
                              hipStream_t stream)
{
  (void)in_sizes; (void)n_in; (void)out_size;
  if (ws_size < (size_t)WS_TOTAL) return;

  const float* x    = (const float*)d_in[0];
  const float* eps  = (const float*)d_in[1];
  const float* Wee  = (const float*)d_in[2];
  const float* bee  = (const float*)d_in[3];
  const float* Wihf = (const float*)d_in[4];
  const float* Whhf = (const float*)d_in[5];
  const float* bihf = (const float*)d_in[6];
  const float* bhhf = (const float*)d_in[7];
  const float* Wihb = (const float*)d_in[8];
  const float* bihb = (const float*)d_in[10];
  const float* bhhb = (const float*)d_in[11];
  const float* Wenc = (const float*)d_in[12];
  const float* benc = (const float*)d_in[13];
  const float* Wz2h = (const float*)d_in[14];
  const float* bz2h = (const float*)d_in[15];
  const float* Wh2i = (const float*)d_in[16];
  const float* bh2i = (const float*)d_in[17];
  const float* Wihd = (const float*)d_in[18];
  const float* Whhd = (const float*)d_in[19];
  const float* bihd = (const float*)d_in[20];
  const float* bhhd = (const float*)d_in[21];
  const float* Wed  = (const float*)d_in[22];
  const float* bed  = (const float*)d_in[23];
  const float* Wdec = (const float*)d_in[24];
  const float* bdec = (const float*)d_in[25];
  char* ws = (char*)d_ws;

  pack_all<<<3193, 256, 0, stream>>>(Wihf, Whhf, Wihb, Wihd, Whhd, Wenc, Wz2h, Wh2i,
                                     Wdec, Wee, Wed, bed, bdec, ws);
  vae_main<<<128, 1024, 0, stream>>>(x, eps, bee, bihf, bhhf, bihb, bhhb, bihd, bhhd,
                                     benc, bz2h, bh2i, bed, bdec, ws, (float*)d_out);
}

// Round 12
// 2054.234 us; speedup vs baseline: 1.4148x; 1.4148x over previous
//
#include <hip/hip_runtime.h>
#include <hip/hip_bf16.h>

typedef __bf16 bf16x8 __attribute__((ext_vector_type(8)));
typedef float  f32x4  __attribute__((ext_vector_type(4)));
typedef unsigned short u16;

#define DEVI __device__ __forceinline__
#define MFMA __builtin_amdgcn_mfma_f32_16x16x32_bf16

DEVI u16 f2bf(float f){
  unsigned u = __builtin_bit_cast(unsigned, f);
  u += 0x7fffu + ((u >> 16) & 1u);
  return (u16)(u >> 16);
}
DEVI float bf2f(u16 h){
  unsigned u = ((unsigned)h) << 16;
  return __builtin_bit_cast(float, u);
}

// ---- ws layout (bytes); bf16 MFMA B-fragments, identity column order ----
enum : int {
  OFF_IHF = 0,                       // Wih_f: (128,768)  KT=4
  OFF_HHF = 196608,                  // Whh_f: (256,768)  KT=8
  OFF_IHB = 589824,                  // Wih_b: (128,768)  KT=4
  OFF_IHD = 786432,                  // Wih_d: (128,768)  KT=4
  OFF_HHD = 983040,                  // Whh_d: (256,768)  KT=8
  OFF_ENC = 1376256,                 // W_enc: (512,128)  KT=16
  OFF_Z2H = 1507328,                 // W_z2h: (64,256)   KT=2
  OFF_H2I = 1540096,                 // W_h2i: (256,64)   KT=8
  OFF_DEC = 1572864,                 // W_dec: (256,32)   KT=8
  OFF_EE  = 1589248,                 // W_ee : (32,128)   KT=1
  OFF_ED  = 1597440,                 // W_ed : (32,64)    KT=1 (unused by main)
  OFF_DE  = 1601536,                 // Wde = Wdec@Wed: (256,64) KT=8
  OFF_BDE = 1634304,                 // bde = bdec@Wed + bed: 64 f32
  WS_TOTAL = 1634560
};

DEVI void packseg(const float* __restrict__ W, u16* __restrict__ dst, int li, int N, int KT){
  int j = li & 7, l = (li >> 3) & 63, f = li >> 9;
  int kt = f % KT, ntg = f / KT;
  int k = kt * 32 + ((l >> 4) << 3) + j;
  int col = (ntg << 4) + (l & 15);
  dst[li] = f2bf(W[k * N + col]);
}

__global__ void pack_all(const float* Wihf, const float* Whhf, const float* Wihb,
                         const float* Wihd, const float* Whhd, const float* Wenc,
                         const float* Wz2h, const float* Wh2i, const float* Wdec,
                         const float* Wee,  const float* Wed,
                         const float* bed,  const float* bdec, char* ws)
{
  int idx = blockIdx.x * 256 + threadIdx.x;
  if (idx < 98304) { packseg(Wihf, (u16*)(ws+OFF_IHF), idx, 768, 4); return; } idx -= 98304;
  if (idx < 196608){ packseg(Whhf, (u16*)(ws+OFF_HHF), idx, 768, 8); return; } idx -= 196608;
  if (idx < 98304) { packseg(Wihb, (u16*)(ws+OFF_IHB), idx, 768, 4); return; } idx -= 98304;
  if (idx < 98304) { packseg(Wihd, (u16*)(ws+OFF_IHD), idx, 768, 4); return; } idx -= 98304;
  if (idx < 196608){ packseg(Whhd, (u16*)(ws+OFF_HHD), idx, 768, 8); return; } idx -= 196608;
  if (idx < 65536) { packseg(Wenc, (u16*)(ws+OFF_ENC), idx, 128, 16); return; } idx -= 65536;
  if (idx < 16384) { packseg(Wz2h, (u16*)(ws+OFF_Z2H), idx, 256, 2); return; } idx -= 16384;
  if (idx < 16384) { packseg(Wh2i, (u16*)(ws+OFF_H2I), idx, 64, 8); return; } idx -= 16384;
  if (idx < 8192)  { packseg(Wdec, (u16*)(ws+OFF_DEC), idx, 32, 8); return; } idx -= 8192;
  if (idx < 4096)  { packseg(Wee,  (u16*)(ws+OFF_EE),  idx, 128, 1); return; } idx -= 4096;
  if (idx < 2048)  { packseg(Wed,  (u16*)(ws+OFF_ED),  idx, 64, 1); return; } idx -= 2048;
  if (idx < 16384){
    int j = idx & 7, l = (idx >> 3) & 63, f = idx >> 9;
    int kt = f & 7, ntg = f >> 3;
    int k = kt * 32 + ((l >> 4) << 3) + j;
    int col = (ntg << 4) + (l & 15);
    float acc = 0.f;
    for (int m = 0; m < 32; ++m) acc += Wdec[k*32 + m] * Wed[m*64 + col];
    ((u16*)(ws+OFF_DE))[idx] = f2bf(acc);
    return;
  } idx -= 16384;
  if (idx < 64){
    float acc = bed[idx];
    for (int m = 0; m < 32; ++m) acc += bdec[m] * Wed[m*64 + idx];
    ((float*)(ws+OFF_BDE))[idx] = acc;
  }
}

// ---- LDS geometry ----
enum : int { RB_A1 = 272, RB_A2 = 528, RB_X = 80 };

DEVI bf16x8 ldF(const char* buf, int row, int kElem, int rowB){
  return *(const bf16x8*)(buf + row * rowB + kElem * 2);
}
DEVI void stBf(char* buf, int row, int col, int rowB, float v){
  *(u16*)(buf + row * rowB + col * 2) = f2bf(v);
}
DEVI float ldBf1(const char* buf, int row, int col, int rowB){
  return bf2f(*(const u16*)(buf + row * rowB + col * 2));
}
DEVI bf16x8 gfrag(const u16* P, int ntg, int KT, int kt, int l){
  return *(const bf16x8*)(P + ((size_t)(ntg * KT + kt) * 64 + l) * 8);
}

// G12T: [1024 cols][16 samples bf16], 32 B rows, XOR-swizzled (bijective)
DEVI int gaddr(int col, int boff){
  int a = col * 32 + boff;
  return a ^ (((col >> 2) & 7) << 4);
}
DEVI void stG(char* g, int col, int g4, const f32x4& a){
  uint2 v;
  v.x = (unsigned)f2bf(a[0]) | ((unsigned)f2bf(a[1]) << 16);
  v.y = (unsigned)f2bf(a[2]) | ((unsigned)f2bf(a[3]) << 16);
  *(uint2*)(g + gaddr(col, g4 * 8)) = v;
}
DEVI void ldG8(const char* g, int col, int sh, float o[8]){
  uint4 v = *(const uint4*)(g + gaddr(col, sh * 16));
  o[0]=bf2f((u16)(v.x&0xffffu)); o[1]=bf2f((u16)(v.x>>16));
  o[2]=bf2f((u16)(v.y&0xffffu)); o[3]=bf2f((u16)(v.y>>16));
  o[4]=bf2f((u16)(v.z&0xffffu)); o[5]=bf2f((u16)(v.z>>16));
  o[6]=bf2f((u16)(v.w&0xffffu)); o[7]=bf2f((u16)(v.w>>16));
}

DEVI float sigm(float x){ return 1.0f / (1.0f + __expf(-x)); }
DEVI float tanh_f(float x){ return 1.0f - 2.0f / (1.0f + __expf(2.0f * x)); }

DEVI void stage_x(const float* __restrict__ xg, int s0, int t, char* Xb, int tid){
  if (tid < 256){
    int s = tid >> 4, d0 = (tid & 15) * 2;
    float2 v = *(const float2*)(xg + (size_t)(s0 + s) * 3200 + t * 32 + d0);
    unsigned pk = (unsigned)f2bf(v.x) | ((unsigned)f2bf(v.y) << 16);
    *(unsigned*)(Xb + s * RB_X + d0 * 2) = pk;
  }
}

// ---- async global->LDS DMA: 16 B/lane, wave-uniform LDS base + lane*16 ----
DEVI void dma16(const u16* g, char* lds){
  __builtin_amdgcn_global_load_lds(
      (const __attribute__((address_space(1))) unsigned*)(const void*)g,
      (__attribute__((address_space(3))) unsigned*)(void*)lds, 16, 0, 0);
}
DEVI bf16x8 ldS(const char* slot, int f, int l){
  return *(const bf16x8*)(slot + f * 1024 + l * 16);
}

// issue one 4-frag (4 KB) chunk of the per-wave weight ring.
// chunks 0-11: group g=ck/3 (gates r0,r1,z0,z1 = cols w+8g), p=ck%3: ih | hh lo | hh hi
// chunks 12,13: in0/in1 ih (ntg w+32, w+40)
// chunks 14-17: hn0/hn1 hh halves (ntg w+32, w+40)
DEVI void issue_chunk(const u16* PIH, const u16* PHH, int w, int l, char* mySTG, int ck){
  char* dst = mySTG + (ck % 3) * 4096;
  const u16* src;
  if (ck < 12){
    int g = ck / 3, p = ck - g * 3;
    int ntg = w + 8 * g;
    src = (p == 0) ? (PIH + (size_t)(ntg * 4) * 512)
                   : (PHH + (size_t)(ntg * 8 + (p - 1) * 4) * 512);
  } else if (ck < 14){
    src = PIH + (size_t)((w + 32 + 8 * (ck - 12)) * 4) * 512;
  } else {
    int gg = (ck - 14) >> 1, half = (ck - 14) & 1;
    src = PHH + (size_t)((w + 32 + 8 * gg) * 8 + half * 4) * 512;
  }
  const u16* g0 = src + l * 8;
  #pragma unroll
  for (int f = 0; f < 4; ++f) dma16(g0 + f * 512, dst + f * 1024);
}

// 128 blocks x 512 threads (8 waves), M=16. LDS ~155 KB => 1 block/CU, 128 VGPR.
// Weight stream: per-wave 3-slot LDS ring via global_load_lds (no VGPR cost).
// RACE FIX (r12): ds_reads of a slot must complete before the DMA that
// overwrites that slot is issued -> s_waitcnt lgkmcnt(0) between ldS and
// issue_chunk (the MFMAs need the same wait anyway; cost ~0).
__global__ __launch_bounds__(512, 1) void vae_main(
    const float* __restrict__ x, const float* __restrict__ eps,
    const float* __restrict__ b_ee,
    const float* __restrict__ bih_f, const float* __restrict__ bhh_f,
    const float* __restrict__ bih_b, const float* __restrict__ bhh_b,
    const float* __restrict__ bih_d, const float* __restrict__ bhh_d,
    const float* __restrict__ b_enc, const float* __restrict__ b_z2h,
    const float* __restrict__ b_h2i, const float* __restrict__ b_ed,
    const float* __restrict__ b_dec,
    const char* __restrict__ ws, float* __restrict__ out)
{
  __shared__ __align__(16) char STG[98304];        // 8 waves x 3 slots x 4 KB
  __shared__ __align__(16) char G12T[32768];
  __shared__ __align__(16) char A1[2][16 * RB_A1]; // 8704
  __shared__ __align__(16) char A2s[16 * RB_A2];   // 8448
  __shared__ __align__(16) char X0b[2][16 * RB_X]; // 2560
  __shared__ float ST[16 * 132];                   // 8448
  // HB (backward h) aliases STG[0..8448) between encoder and decoder rings.

  const int tid = threadIdx.x;
  const int l = tid & 63;
  const int w = tid >> 6;       // wave 0..7
  const int cc = l & 15;
  const int g4 = l >> 4;
  const int s0 = blockIdx.x * 16;
  const int u_ = tid & 255;
  const int sh = tid >> 8;      // sample half (8 samples)

  const u16* PIHF = (const u16*)(ws + OFF_IHF);
  const u16* PHHF = (const u16*)(ws + OFF_HHF);
  const u16* PIHB = (const u16*)(ws + OFF_IHB);
  const u16* PIHD = (const u16*)(ws + OFF_IHD);
  const u16* PHHD = (const u16*)(ws + OFF_HHD);
  const u16* PENC = (const u16*)(ws + OFF_ENC);
  const u16* PZ2H = (const u16*)(ws + OFF_Z2H);
  const u16* PH2I = (const u16*)(ws + OFF_H2I);
  const u16* PDEC = (const u16*)(ws + OFF_DEC);
  const u16* PEE  = (const u16*)(ws + OFF_EE);
  const u16* PDE  = (const u16*)(ws + OFF_DE);

  const f32x4 zf = {0.f, 0.f, 0.f, 0.f};
  char* mySTG = STG + (size_t)w * 12288;

  float brX = bih_f[u_] + bhh_f[u_];
  float bzX = bih_f[256 + u_] + bhh_f[256 + u_];
  float binX = bih_f[512 + u_], bhnX = bhh_f[512 + u_];
  const float beer = b_ee[16 * w + cc];
  const bf16x8 bEE = gfrag(PEE, w, 1, 0, l);

  float hreg[8];
  #pragma unroll
  for (int i = 0; i < 8; ++i) hreg[i] = 0.f;

  // ---------------- prologue ----------------
  stage_x(x, s0, 0, X0b[0], tid);
  for (int i = tid; i < 16 * RB_A2 / 4; i += 512) ((unsigned*)A2s)[i] = 0u;
  __syncthreads();
  {
    bf16x8 a = ldF(X0b[0], cc, g4 * 8, RB_X);
    f32x4 xa = MFMA(a, bEE, zf, 0, 0, 0);
    #pragma unroll
    for (int q = 0; q < 4; ++q)
      stBf(A1[0], g4 * 4 + q, 16 * w + cc, RB_A1, fmaxf(xa[q] + beer, 0.f));
  }
  stage_x(x, s0, 1, X0b[1], tid);
  issue_chunk(PIHF, PHHF, w, l, mySTG, 0);
  issue_chunk(PIHF, PHHF, w, l, mySTG, 1);
  issue_chunk(PIHF, PHHF, w, l, mySTG, 2);
  __syncthreads();

  // ---------------- encoder: 100 steps ----------------
  for (int t = 0; t < 100; ++t){
    bf16x8 a1f[4], a2f[8];
    #pragma unroll
    for (int kt = 0; kt < 4; ++kt) a1f[kt] = ldF(A1[t & 1], cc, kt * 32 + g4 * 8, RB_A1);
    #pragma unroll
    for (int kt = 0; kt < 8; ++kt) a2f[kt] = ldF(A2s, cc, kt * 32 + g4 * 8, RB_A2);

    f32x4 acc = zf;
    #pragma unroll 1
    for (int ck = 0; ck < 18; ++ck){
      char* slot = mySTG + (ck % 3) * 4096;
      asm volatile("s_waitcnt vmcnt(8)" ::: "memory");
      bf16x8 f0 = ldS(slot, 0, l), f1 = ldS(slot, 1, l);
      bf16x8 f2 = ldS(slot, 2, l), f3 = ldS(slot, 3, l);
      asm volatile("s_waitcnt lgkmcnt(0)" ::: "memory");   // reads done before overwrite
      int nc = ck + 3; if (nc >= 18) nc -= 18;
      issue_chunk(PIHF, PHHF, w, l, mySTG, nc);
      if (ck < 12){
        const int g = ck / 3, p = ck - g * 3;
        if (p == 0){
          acc = zf;
          acc = MFMA(a1f[0], f0, acc, 0,0,0); acc = MFMA(a1f[1], f1, acc, 0,0,0);
          acc = MFMA(a1f[2], f2, acc, 0,0,0); acc = MFMA(a1f[3], f3, acc, 0,0,0);
        } else if (p == 1){
          acc = MFMA(a2f[0], f0, acc, 0,0,0); acc = MFMA(a2f[1], f1, acc, 0,0,0);
          acc = MFMA(a2f[2], f2, acc, 0,0,0); acc = MFMA(a2f[3], f3, acc, 0,0,0);
        } else {
          acc = MFMA(a2f[4], f0, acc, 0,0,0); acc = MFMA(a2f[5], f1, acc, 0,0,0);
          acc = MFMA(a2f[6], f2, acc, 0,0,0); acc = MFMA(a2f[7], f3, acc, 0,0,0);
          stG(G12T, 16 * (w + 8 * g) + cc, g4, acc);
        }
      } else if (ck < 14){
        acc = zf;
        acc = MFMA(a1f[0], f0, acc, 0,0,0); acc = MFMA(a1f[1], f1, acc, 0,0,0);
        acc = MFMA(a1f[2], f2, acc, 0,0,0); acc = MFMA(a1f[3], f3, acc, 0,0,0);
        stG(G12T, 16 * (w + 32 + 8 * (ck - 12)) + cc, g4, acc);
      } else {
        if (((ck - 14) & 1) == 0){
          acc = zf;
          acc = MFMA(a2f[0], f0, acc, 0,0,0); acc = MFMA(a2f[1], f1, acc, 0,0,0);
          acc = MFMA(a2f[2], f2, acc, 0,0,0); acc = MFMA(a2f[3], f3, acc, 0,0,0);
        } else {
          acc = MFMA(a2f[4], f0, acc, 0,0,0); acc = MFMA(a2f[5], f1, acc, 0,0,0);
          acc = MFMA(a2f[6], f2, acc, 0,0,0); acc = MFMA(a2f[7], f3, acc, 0,0,0);
          stG(G12T, 16 * (w + 48 + 8 * ((ck - 14) >> 1)) + cc, g4, acc);
        }
      }
    }
    if (t < 99){
      bf16x8 a = ldF(X0b[(t + 1) & 1], cc, g4 * 8, RB_X);
      f32x4 xa = MFMA(a, bEE, zf, 0, 0, 0);
      #pragma unroll
      for (int q = 0; q < 4; ++q)
        stBf(A1[(t + 1) & 1], g4 * 4 + q, 16 * w + cc, RB_A1, fmaxf(xa[q] + beer, 0.f));
    }
    if (t < 98) stage_x(x, s0, t + 2, X0b[t & 1], tid);
    __syncthreads();

    { // combine: thread owns (unit u_, 8 samples)
      float gr[8], gz[8], gi[8], gh[8];
      ldG8(G12T, u_,        sh, gr);
      ldG8(G12T, 256 + u_,  sh, gz);
      ldG8(G12T, 512 + u_,  sh, gi);
      ldG8(G12T, 768 + u_,  sh, gh);
      #pragma unroll
      for (int i = 0; i < 8; ++i){
        float r  = sigm(gr[i] + brX);
        float zz = sigm(gz[i] + bzX);
        float n  = tanh_f(gi[i] + binX + r * (gh[i] + bhnX));
        float h  = (1.f - zz) * n + zz * hreg[i];
        hreg[i] = h;
        stBf(A2s, sh * 8 + i, u_, RB_A2, h);
      }
    }
    __syncthreads();
  }

  asm volatile("s_waitcnt vmcnt(0)" ::: "memory");   // drain enc ring tail

  // ---------------- backward cell (h0=0), gi from xe_99 in A1[1] ----------------
  {
    bf16x8 a1f[4];
    #pragma unroll
    for (int kt = 0; kt < 4; ++kt) a1f[kt] = ldF(A1[1], cc, kt * 32 + g4 * 8, RB_A1);
    #pragma unroll
    for (int j = 0; j < 6; ++j){
      const int G = w + 8 * j;
      f32x4 acc = zf;
      #pragma unroll
      for (int kt = 0; kt < 4; ++kt) acc = MFMA(a1f[kt], gfrag(PIHB, G, 4, kt, l), acc, 0, 0, 0);
      stG(G12T, 16 * G + cc, g4, acc);
    }
  }
  __syncthreads();
  { // backward combine -> HB (aliases STG)
    const float brb = bih_b[u_] + bhh_b[u_];
    const float bzb = bih_b[256 + u_] + bhh_b[256 + u_];
    const float binb = bih_b[512 + u_], bhnb = bhh_b[512 + u_];
    float gr[8], gz[8], gi[8];
    ldG8(G12T, u_,       sh, gr);
    ldG8(G12T, 256 + u_, sh, gz);
    ldG8(G12T, 512 + u_, sh, gi);
    #pragma unroll
    for (int i = 0; i < 8; ++i){
      float r  = sigm(gr[i] + brb);
      float zz = sigm(gz[i] + bzb);
      float n  = tanh_f(gi[i] + binb + r * bhnb);
      stBf(STG, sh * 8 + i, u_, RB_A2, (1.f - zz) * n);
    }
  }
  __syncthreads();

  // ---------------- stats = [h_fwd | h_bwd] @ W_enc + b_enc ----------------
  {
    f32x4 sa = zf;
    #pragma unroll
    for (int kt = 0; kt < 8; ++kt)
      sa = MFMA(ldF(A2s, cc, kt * 32 + g4 * 8, RB_A2), gfrag(PENC, w, 16, kt, l), sa, 0, 0, 0);
    #pragma unroll
    for (int kt = 8; kt < 16; ++kt)
      sa = MFMA(ldF(STG, cc, (kt - 8) * 32 + g4 * 8, RB_A2), gfrag(PENC, w, 16, kt, l), sa, 0, 0, 0);
    const float be = b_enc[16 * w + cc];
    #pragma unroll
    for (int q = 0; q < 4; ++q)
      ST[(g4 * 4 + q) * 132 + 16 * w + cc] = sa[q] + be;
  }
  __syncthreads();

  // ---------------- z; write mu/logvar ----------------
  {
    const int s = tid >> 5, jj = (tid & 31) * 2;
    #pragma unroll
    for (int d = 0; d < 2; ++d){
      const int j = jj + d;
      float mu = ST[s * 132 + j], lv = ST[s * 132 + 64 + j];
      out[6553600u + (size_t)(s0 + s) * 64 + j] = mu;
      out[6684672u + (size_t)(s0 + s) * 64 + j] = lv;
      float zv = mu + __expf(0.5f * lv) * eps[(size_t)(s0 + s) * 64 + j];
      stBf(A1[0], s, j, RB_A1, zv);
    }
  }
  __syncthreads();

  // ---------------- h_dec0 = relu(z @ W_z2h + b_z2h) -> A2s; dec biases ----------------
  {
    #pragma unroll
    for (int jj = 0; jj < 2; ++jj){
      const int g = w + 8 * jj;
      f32x4 da = zf;
      #pragma unroll
      for (int kt = 0; kt < 2; ++kt)
        da = MFMA(ldF(A1[0], cc, kt * 32 + g4 * 8, RB_A1), gfrag(PZ2H, g, 2, kt, l), da, 0, 0, 0);
      const float bz = b_z2h[16 * g + cc];
      #pragma unroll
      for (int q = 0; q < 4; ++q)
        stBf(A2s, g4 * 4 + q, 16 * g + cc, RB_A2, fmaxf(da[q] + bz, 0.f));
    }
    brX = bih_d[u_] + bhh_d[u_];
    bzX = bih_d[256 + u_] + bhh_d[256 + u_];
    binX = bih_d[512 + u_]; bhnX = bhh_d[512 + u_];
  }
  __syncthreads();

  const float bh2ir = (w < 4) ? b_h2i[16 * w + cc] : 0.f;
  const float bder  = (w >= 4) ? ((const float*)(ws + OFF_BDE))[16 * (w - 4) + cc] : 0.f;
  const float bdecr = (w == 2 || w == 3) ? b_dec[16 * (w - 2) + cc] : 0.f;

  // ---------------- hd preload, hid0 (w<4), cur0 ----------------
  #pragma unroll
  for (int i = 0; i < 8; ++i) hreg[i] = ldBf1(A2s, sh * 8 + i, u_, RB_A2);
  if (w < 4){
    f32x4 ha = zf;
    #pragma unroll
    for (int kt = 0; kt < 8; ++kt)
      ha = MFMA(ldF(A2s, cc, kt * 32 + g4 * 8, RB_A2), gfrag(PH2I, w, 8, kt, l), ha, 0, 0, 0);
    #pragma unroll
    for (int q = 0; q < 4; ++q)
      stBf(A1[0], g4 * 4 + q, 64 + 16 * w + cc, RB_A1, fmaxf(ha[q] + bh2ir, 0.f));
  }
  {
    const int s = tid >> 5, jj = (tid & 31) * 2;
    #pragma unroll
    for (int d = 0; d < 2; ++d)
      stBf(A1[0], s, jj + d, RB_A1, fmaxf(b_ed[jj + d], 0.f));
  }
  issue_chunk(PIHD, PHHD, w, l, mySTG, 0);
  issue_chunk(PIHD, PHHD, w, l, mySTG, 1);
  issue_chunk(PIHD, PHHD, w, l, mySTG, 2);
  __syncthreads();

  // ---------------- decoder: 100 steps ----------------
  for (int t = 0; t < 100; ++t){
    bf16x8 a1f[4], a2f[8];
    #pragma unroll
    for (int kt = 0; kt < 4; ++kt) a1f[kt] = ldF(A1[0], cc, kt * 32 + g4 * 8, RB_A1);
    #pragma unroll
    for (int kt = 0; kt < 8; ++kt) a2f[kt] = ldF(A2s, cc, kt * 32 + g4 * 8, RB_A2);

    f32x4 acc = zf;
    #pragma unroll 1
    for (int ck = 0; ck < 18; ++ck){
      char* slot = mySTG + (ck % 3) * 4096;
      asm volatile("s_waitcnt vmcnt(8)" ::: "memory");
      bf16x8 f0 = ldS(slot, 0, l), f1 = ldS(slot, 1, l);
      bf16x8 f2 = ldS(slot, 2, l), f3 = ldS(slot, 3, l);
      asm volatile("s_waitcnt lgkmcnt(0)" ::: "memory");   // reads done before overwrite
      int nc = ck + 3; if (nc >= 18) nc -= 18;
      issue_chunk(PIHD, PHHD, w, l, mySTG, nc);
      if (ck < 12){
        const int g = ck / 3, p = ck - g * 3;
        if (p == 0){
          acc = zf;
          acc = MFMA(a1f[0], f0, acc, 0,0,0); acc = MFMA(a1f[1], f1, acc, 0,0,0);
          acc = MFMA(a1f[2], f2, acc, 0,0,0); acc = MFMA(a1f[3], f3, acc, 0,0,0);
        } else if (p == 1){
          acc = MFMA(a2f[0], f0, acc, 0,0,0); acc = MFMA(a2f[1], f1, acc, 0,0,0);
          acc = MFMA(a2f[2], f2, acc, 0,0,0); acc = MFMA(a2f[3], f3, acc, 0,0,0);
        } else {
          acc = MFMA(a2f[4], f0, acc, 0,0,0); acc = MFMA(a2f[5], f1, acc, 0,0,0);
          acc = MFMA(a2f[6], f2, acc, 0,0,0); acc = MFMA(a2f[7], f3, acc, 0,0,0);
          stG(G12T, 16 * (w + 8 * g) + cc, g4, acc);
        }
      } else if (ck < 14){
        acc = zf;
        acc = MFMA(a1f[0], f0, acc, 0,0,0); acc = MFMA(a1f[1], f1, acc, 0,0,0);
        acc = MFMA(a1f[2], f2, acc, 0,0,0); acc = MFMA(a1f[3], f3, acc, 0,0,0);
        stG(G12T, 16 * (w + 32 + 8 * (ck - 12)) + cc, g4, acc);
      } else {
        if (((ck - 14) & 1) == 0){
          acc = zf;
          acc = MFMA(a2f[0], f0, acc, 0,0,0); acc = MFMA(a2f[1], f1, acc, 0,0,0);
          acc = MFMA(a2f[2], f2, acc, 0,0,0); acc = MFMA(a2f[3], f3, acc, 0,0,0);
        } else {
          acc = MFMA(a2f[4], f0, acc, 0,0,0); acc = MFMA(a2f[5], f1, acc, 0,0,0);
          acc = MFMA(a2f[6], f2, acc, 0,0,0); acc = MFMA(a2f[7], f3, acc, 0,0,0);
          stG(G12T, 16 * (w + 48 + 8 * ((ck - 14) >> 1)) + cc, g4, acc);
        }
      }
    }
    __syncthreads();

    { // combine -> h2
      float gr[8], gz[8], gi[8], gh[8];
      ldG8(G12T, u_,        sh, gr);
      ldG8(G12T, 256 + u_,  sh, gz);
      ldG8(G12T, 512 + u_,  sh, gi);
      ldG8(G12T, 768 + u_,  sh, gh);
      #pragma unroll
      for (int i = 0; i < 8; ++i){
        float r  = sigm(gr[i] + brX);
        float zz = sigm(gz[i] + bzX);
        float n  = tanh_f(gi[i] + binX + r * (gh[i] + bhnX));
        float h  = (1.f - zz) * n + zz * hreg[i];
        hreg[i] = h;
        stBf(A2s, sh * 8 + i, u_, RB_A2, h);
      }
    }
    __syncthreads();

    // heads: w0-3 h2i -> A1 hi; w4-7 fused cur (Wde) -> A1 lo; w2-3 also x_cur -> out
    {
      bf16x8 af[8];
      #pragma unroll
      for (int kt = 0; kt < 8; ++kt) af[kt] = ldF(A2s, cc, kt * 32 + g4 * 8, RB_A2);
      f32x4 hv = zf;
      if (w < 4){
        #pragma unroll
        for (int kt = 0; kt < 8; ++kt) hv = MFMA(af[kt], gfrag(PH2I, w, 8, kt, l), hv, 0, 0, 0);
        #pragma unroll
        for (int q = 0; q < 4; ++q)
          stBf(A1[0], g4 * 4 + q, 64 + 16 * w + cc, RB_A1, fmaxf(hv[q] + bh2ir, 0.f));
      } else {
        #pragma unroll
        for (int kt = 0; kt < 8; ++kt) hv = MFMA(af[kt], gfrag(PDE, w - 4, 8, kt, l), hv, 0, 0, 0);
        #pragma unroll
        for (int q = 0; q < 4; ++q)
          stBf(A1[0], g4 * 4 + q, 16 * (w - 4) + cc, RB_A1, fmaxf(hv[q] + bder, 0.f));
      }
      if (w == 2 || w == 3){
        f32x4 xc = zf;
        #pragma unroll
        for (int kt = 0; kt < 8; ++kt) xc = MFMA(af[kt], gfrag(PDEC, w - 2, 8, kt, l), xc, 0, 0, 0);
        #pragma unroll
        for (int q = 0; q < 4; ++q)
          out[(size_t)(s0 + g4 * 4 + q) * 3200 + t * 32 + 16 * (w - 2) + cc] = xc[q] + bdecr;
      }
    }
    __syncthreads();
  }
}

extern "C" void kernel_launch(void* const* d_in, const int* in_sizes, int n_in,
                              void* d_out, int out_size, void* d_ws, size_t ws_size,
                              hipStream_t stream)
{
  (void)in_sizes; (void)n_in; (void)out_size;
  if (ws_size < (size_t)WS_TOTAL) return;

  const float* x    = (const float*)d_in[0];
  const float* eps  = (const float*)d_in[1];
  const float* Wee  = (const float*)d_in[2];
  const float* bee  = (const float*)d_in[3];
  const float* Wihf = (const float*)d_in[4];
  const float* Whhf = (const float*)d_in[5];
  const float* bihf = (const float*)d_in[6];
  const float* bhhf = (const float*)d_in[7];
  const float* Wihb = (const float*)d_in[8];
  const float* bihb = (const float*)d_in[10];
  const float* bhhb = (const float*)d_in[11];
  const float* Wenc = (const float*)d_in[12];
  const float* benc = (const float*)d_in[13];
  const float* Wz2h = (const float*)d_in[14];
  const float* bz2h = (const float*)d_in[15];
  const float* Wh2i = (const float*)d_in[16];
  const float* bh2i = (const float*)d_in[17];
  const float* Wihd = (const float*)d_in[18];
  const float* Whhd = (const float*)d_in[19];
  const float* bihd = (const float*)d_in[20];
  const float* bhhd = (const float*)d_in[21];
  const float* Wed  = (const float*)d_in[22];
  const float* bed  = (const float*)d_in[23];
  const float* Wdec = (const float*)d_in[24];
  const float* bdec = (const float*)d_in[25];
  char* ws = (char*)d_ws;

  pack_all<<<3193, 256, 0, stream>>>(Wihf, Whhf, Wihb, Wihd, Whhd, Wenc, Wz2h, Wh2i,
                                     Wdec, Wee, Wed, bed, bdec, ws);
  vae_main<<<128, 512, 0, stream>>>(x, eps, bee, bihf, bhhf, bihb, bhhb, bihd, bhhd,
                                    benc, bz2h, bh2i, bed, bdec, ws, (float*)d_out);
}

// Round 14
// 1594.659 us; speedup vs baseline: 1.8225x; 1.2882x over previous
//
#include <hip/hip_runtime.h>
#include <hip/hip_bf16.h>

typedef __bf16 bf16x8 __attribute__((ext_vector_type(8)));
typedef float  f32x4  __attribute__((ext_vector_type(4)));
typedef unsigned short u16;

#define DEVI __device__ __forceinline__
#define MFMA __builtin_amdgcn_mfma_f32_16x16x32_bf16

DEVI u16 f2bf(float f){
  unsigned u = __builtin_bit_cast(unsigned, f);
  u += 0x7fffu + ((u >> 16) & 1u);
  return (u16)(u >> 16);
}
DEVI float bf2f(u16 h){
  unsigned u = ((unsigned)h) << 16;
  return __builtin_bit_cast(float, u);
}

// ---- ws layout (bytes); bf16 MFMA B-fragments, identity column order ----
enum : int {
  OFF_IHF = 0,                       // Wih_f: (128,768)  KT=4
  OFF_HHF = 196608,                  // Whh_f: (256,768)  KT=8
  OFF_IHB = 589824,                  // Wih_b: (128,768)  KT=4
  OFF_IHD = 786432,                  // Wih_d: (128,768)  KT=4
  OFF_HHD = 983040,                  // Whh_d: (256,768)  KT=8
  OFF_ENC = 1376256,                 // W_enc: (512,128)  KT=16
  OFF_Z2H = 1507328,                 // W_z2h: (64,256)   KT=2
  OFF_H2I = 1540096,                 // W_h2i: (256,64)   KT=8
  OFF_DEC = 1572864,                 // W_dec: (256,32)   KT=8
  OFF_EE  = 1589248,                 // W_ee : (32,128)   KT=1
  OFF_ED  = 1597440,                 // W_ed : (32,64)    KT=1 (unused by main)
  OFF_DE  = 1601536,                 // Wde = Wdec@Wed: (256,64) KT=8
  OFF_BDE = 1634304,                 // bde = bdec@Wed + bed: 64 f32
  WS_TOTAL = 1634560
};

DEVI void packseg(const float* __restrict__ W, u16* __restrict__ dst, int li, int N, int KT){
  int j = li & 7, l = (li >> 3) & 63, f = li >> 9;
  int kt = f % KT, ntg = f / KT;
  int k = kt * 32 + ((l >> 4) << 3) + j;
  int col = (ntg << 4) + (l & 15);
  dst[li] = f2bf(W[k * N + col]);
}

__global__ void pack_all(const float* Wihf, const float* Whhf, const float* Wihb,
                         const float* Wihd, const float* Whhd, const float* Wenc,
                         const float* Wz2h, const float* Wh2i, const float* Wdec,
                         const float* Wee,  const float* Wed,
                         const float* bed,  const float* bdec, char* ws)
{
  int idx = blockIdx.x * 256 + threadIdx.x;
  if (idx < 98304) { packseg(Wihf, (u16*)(ws+OFF_IHF), idx, 768, 4); return; } idx -= 98304;
  if (idx < 196608){ packseg(Whhf, (u16*)(ws+OFF_HHF), idx, 768, 8); return; } idx -= 196608;
  if (idx < 98304) { packseg(Wihb, (u16*)(ws+OFF_IHB), idx, 768, 4); return; } idx -= 98304;
  if (idx < 98304) { packseg(Wihd, (u16*)(ws+OFF_IHD), idx, 768, 4); return; } idx -= 98304;
  if (idx < 196608){ packseg(Whhd, (u16*)(ws+OFF_HHD), idx, 768, 8); return; } idx -= 196608;
  if (idx < 65536) { packseg(Wenc, (u16*)(ws+OFF_ENC), idx, 128, 16); return; } idx -= 65536;
  if (idx < 16384) { packseg(Wz2h, (u16*)(ws+OFF_Z2H), idx, 256, 2); return; } idx -= 16384;
  if (idx < 16384) { packseg(Wh2i, (u16*)(ws+OFF_H2I), idx, 64, 8); return; } idx -= 16384;
  if (idx < 8192)  { packseg(Wdec, (u16*)(ws+OFF_DEC), idx, 32, 8); return; } idx -= 8192;
  if (idx < 4096)  { packseg(Wee,  (u16*)(ws+OFF_EE),  idx, 128, 1); return; } idx -= 4096;
  if (idx < 2048)  { packseg(Wed,  (u16*)(ws+OFF_ED),  idx, 64, 1); return; } idx -= 2048;
  if (idx < 16384){
    int j = idx & 7, l = (idx >> 3) & 63, f = idx >> 9;
    int kt = f & 7, ntg = f >> 3;
    int k = kt * 32 + ((l >> 4) << 3) + j;
    int col = (ntg << 4) + (l & 15);
    float acc = 0.f;
    for (int m = 0; m < 32; ++m) acc += Wdec[k*32 + m] * Wed[m*64 + col];
    ((u16*)(ws+OFF_DE))[idx] = f2bf(acc);
    return;
  } idx -= 16384;
  if (idx < 64){
    float acc = bed[idx];
    for (int m = 0; m < 32; ++m) acc += bdec[m] * Wed[m*64 + idx];
    ((float*)(ws+OFF_BDE))[idx] = acc;
  }
}

// ---- LDS geometry ----
enum : int { RB_A1 = 272, RB_A2 = 528, RB_X = 80 };

DEVI bf16x8 ldF(const char* buf, int row, int kElem, int rowB){
  return *(const bf16x8*)(buf + row * rowB + kElem * 2);
}
DEVI void stBf(char* buf, int row, int col, int rowB, float v){
  *(u16*)(buf + row * rowB + col * 2) = f2bf(v);
}
DEVI bf16x8 gfrag(const u16* P, int ntg, int KT, int kt, int l){
  return *(const bf16x8*)(P + ((size_t)(ntg * KT + kt) * 64 + l) * 8);
}

DEVI float sigm(float x){ return 1.0f / (1.0f + __expf(-x)); }
DEVI float tanh_f(float x){ return 1.0f - 2.0f / (1.0f + __expf(2.0f * x)); }

DEVI void stage_x(const float* __restrict__ xg, int s0, int t, char* Xb, int tid){
  if (tid < 256){
    int s = tid >> 4, d0 = (tid & 15) * 2;
    float2 v = *(const float2*)(xg + (size_t)(s0 + s) * 3200 + t * 32 + d0);
    unsigned pk = (unsigned)f2bf(v.x) | ((unsigned)f2bf(v.y) << 16);
    *(unsigned*)(Xb + s * RB_X + d0 * 2) = pk;
  }
}

// ---- async global->LDS DMA: 16 B/lane, wave-uniform LDS base + lane*16 ----
DEVI void dma16(const u16* g, char* lds){
  __builtin_amdgcn_global_load_lds(
      (const __attribute__((address_space(1))) unsigned*)(const void*)g,
      (__attribute__((address_space(3))) unsigned*)(void*)lds, 16, 0, 0);
}
DEVI bf16x8 ldS(const char* slot, int f, int l){
  return *(const bf16x8*)(slot + f * 1024 + l * 16);
}
DEVI void issue4(const u16* src, char* dst, int l){
  const u16* g0 = src + l * 8;
  dma16(g0, dst); dma16(g0 + 512, dst + 1024);
  dma16(g0 + 1024, dst + 2048); dma16(g0 + 1536, dst + 3072);
}

// chunk source helpers (4-frag chunks; ih = 4 frags, hh lo/hi = 4 frags each)
DEVI const u16* srcIH(const u16* PI, int ntg){ return PI + (size_t)ntg * 2048; }
DEVI const u16* srcHL(const u16* PH, int ntg){ return PH + (size_t)ntg * 4096; }
DEVI const u16* srcHH(const u16* PH, int ntg){ return PH + (size_t)ntg * 4096 + 2048; }

// ring iteration, hh-type: A-frags passed by value (a2f regs)
DEVI void rit_hh(char* slot, const u16* nsrc, int l, f32x4& acc, bool zero,
                 bf16x8 p0, bf16x8 p1, bf16x8 p2, bf16x8 p3){
  asm volatile("s_waitcnt vmcnt(12)" ::: "memory");
  bf16x8 f0 = ldS(slot, 0, l), f1 = ldS(slot, 1, l);
  bf16x8 f2 = ldS(slot, 2, l), f3 = ldS(slot, 3, l);
  asm volatile("s_waitcnt lgkmcnt(0)" ::: "memory");
  issue4(nsrc, slot, l);
  if (zero) acc = (f32x4){0.f, 0.f, 0.f, 0.f};
  acc = MFMA(p0, f0, acc, 0,0,0); acc = MFMA(p1, f1, acc, 0,0,0);
  acc = MFMA(p2, f2, acc, 0,0,0); acc = MFMA(p3, f3, acc, 0,0,0);
}
// ring iteration, ih-type: reads A-frags from A1 LDS (always zero-init)
DEVI void rit_ih(char* slot, const u16* nsrc, int l, int cc, int g4,
                 const char* Ab, f32x4& acc){
  asm volatile("s_waitcnt vmcnt(12)" ::: "memory");
  bf16x8 f0 = ldS(slot, 0, l), f1 = ldS(slot, 1, l);
  bf16x8 f2 = ldS(slot, 2, l), f3 = ldS(slot, 3, l);
  bf16x8 a0 = ldF(Ab, cc, 0  + g4 * 8, RB_A1);
  bf16x8 a1 = ldF(Ab, cc, 32 + g4 * 8, RB_A1);
  bf16x8 a2 = ldF(Ab, cc, 64 + g4 * 8, RB_A1);
  bf16x8 a3 = ldF(Ab, cc, 96 + g4 * 8, RB_A1);
  asm volatile("s_waitcnt lgkmcnt(0)" ::: "memory");
  issue4(nsrc, slot, l);
  acc = (f32x4){0.f, 0.f, 0.f, 0.f};
  acc = MFMA(a0, f0, acc, 0,0,0); acc = MFMA(a1, f1, acc, 0,0,0);
  acc = MFMA(a2, f2, acc, 0,0,0); acc = MFMA(a3, f3, acc, 0,0,0);
}

// 128 blocks x 512 threads (8 waves), M=16, 1 block/CU (LDS ~151 KB).
// Wave w owns gate col-groups {w,w+8,...,w+56}: r/z/in/hn for units
// u0=16w+(l&15), u1=u0+128 -> GRU combine is LANE-LOCAL (no G12T).
// Weights stream global->LDS via 4-slot/wave ring (4KB chunks, 18/step).
// r14 FIX: 18 iters % 4 slots != 0 -> the last 4 issues of each step must
// target next step's FIRST reads of those slots (order it2,it3,it0,it1),
// i.e. sources hh(w), ih(w+8), ih(w), hl(w) -- r13 had them rotated by 2.
__global__ __launch_bounds__(512, 1) void vae_main(
    const float* __restrict__ x, const float* __restrict__ eps,
    const float* __restrict__ b_ee,
    const float* __restrict__ bih_f, const float* __restrict__ bhh_f,
    const float* __restrict__ bih_b, const float* __restrict__ bhh_b,
    const float* __restrict__ bih_d, const float* __restrict__ bhh_d,
    const float* __restrict__ b_enc, const float* __restrict__ b_z2h,
    const float* __restrict__ b_h2i, const float* __restrict__ b_ed,
    const float* __restrict__ b_dec,
    const char* __restrict__ ws, float* __restrict__ out)
{
  __shared__ __align__(16) char STG[131072];       // 8 waves x 4 slots x 4 KB
  __shared__ __align__(16) char A1[2][16 * RB_A1]; // 8704
  __shared__ __align__(16) char A2s[16 * RB_A2];   // 8448
  __shared__ __align__(16) char X0b[2][16 * RB_X]; // 2560
  // HB (h_bwd) aliases STG[0..8448); ST (stats f32) aliases STG+65536.

  const int tid = threadIdx.x;
  const int l = tid & 63;
  const int w = tid >> 6;       // wave 0..7
  const int cc = l & 15;
  const int g4 = l >> 4;
  const int s0 = blockIdx.x * 16;

  const u16* PIHF = (const u16*)(ws + OFF_IHF);
  const u16* PHHF = (const u16*)(ws + OFF_HHF);
  const u16* PIHB = (const u16*)(ws + OFF_IHB);
  const u16* PIHD = (const u16*)(ws + OFF_IHD);
  const u16* PHHD = (const u16*)(ws + OFF_HHD);
  const u16* PENC = (const u16*)(ws + OFF_ENC);
  const u16* PZ2H = (const u16*)(ws + OFF_Z2H);
  const u16* PH2I = (const u16*)(ws + OFF_H2I);
  const u16* PDEC = (const u16*)(ws + OFF_DEC);
  const u16* PEE  = (const u16*)(ws + OFF_EE);
  const u16* PDE  = (const u16*)(ws + OFF_DE);

  const f32x4 zf = {0.f, 0.f, 0.f, 0.f};
  char* S0 = STG + (size_t)w * 16384;
  char* S1 = S0 + 4096; char* S2 = S0 + 8192; char* S3 = S0 + 12288;
  char* HBb = STG;                       // h_bwd buffer alias
  float* ST = (float*)(STG + 65536);     // stats alias

  // lane-local unit ids and gate biases (encoder set now)
  const int u0 = 16 * w + cc, u1 = u0 + 128;
  float br0 = bih_f[u0] + bhh_f[u0],       br1 = bih_f[u1] + bhh_f[u1];
  float bz0 = bih_f[256+u0] + bhh_f[256+u0], bz1 = bih_f[256+u1] + bhh_f[256+u1];
  float bi0 = bih_f[512+u0], bi1 = bih_f[512+u1];
  float bh0 = bhh_f[512+u0], bh1 = bhh_f[512+u1];
  const float beer = b_ee[u0];
  const bf16x8 bEE = gfrag(PEE, w, 1, 0, l);

  float hr[8];                           // lane-local h carry: [j*4+q]
  #pragma unroll
  for (int i = 0; i < 8; ++i) hr[i] = 0.f;

  // ---------------- prologue ----------------
  stage_x(x, s0, 0, X0b[0], tid);
  for (int i = tid; i < 16 * RB_A2 / 4; i += 512) ((unsigned*)A2s)[i] = 0u;
  __syncthreads();
  {
    bf16x8 a = ldF(X0b[0], cc, g4 * 8, RB_X);
    f32x4 xa = MFMA(a, bEE, zf, 0, 0, 0);
    #pragma unroll
    for (int q = 0; q < 4; ++q)
      stBf(A1[0], g4 * 4 + q, u0, RB_A1, fmaxf(xa[q] + beer, 0.f));
  }
  stage_x(x, s0, 1, X0b[1], tid);
  issue4(srcIH(PIHF, w), S0, l);       // it0: r0-ih
  issue4(srcHL(PHHF, w), S1, l);       // it1: r0-hh-lo
  issue4(srcHH(PHHF, w), S2, l);       // it2: r0-hh-hi
  issue4(srcIH(PIHF, w + 8), S3, l);   // it3: r1-ih
  __syncthreads();

  f32x4 aR0, aR1, aZ0, aZ1, aI0, aI1, aH0, aH1;

  // ---------------- encoder: 100 steps ----------------
  for (int t = 0; t < 100; ++t){
    const char* Ab = A1[t & 1];
    bf16x8 a2f[8];
    #pragma unroll
    for (int kt = 0; kt < 8; ++kt) a2f[kt] = ldF(A2s, cc, kt * 32 + g4 * 8, RB_A2);

    rit_ih(S0, srcHL(PHHF, w + 8),  l, cc, g4, Ab, aR0);
    rit_hh(S1, srcHH(PHHF, w + 8),  l, aR0, false, a2f[0], a2f[1], a2f[2], a2f[3]);
    rit_hh(S2, srcIH(PIHF, w + 16), l, aR0, false, a2f[4], a2f[5], a2f[6], a2f[7]);
    rit_ih(S3, srcHL(PHHF, w + 16), l, cc, g4, Ab, aR1);
    rit_hh(S0, srcHH(PHHF, w + 16), l, aR1, false, a2f[0], a2f[1], a2f[2], a2f[3]);
    rit_hh(S1, srcIH(PIHF, w + 24), l, aR1, false, a2f[4], a2f[5], a2f[6], a2f[7]);
    rit_ih(S2, srcHL(PHHF, w + 24), l, cc, g4, Ab, aZ0);
    rit_hh(S3, srcHH(PHHF, w + 24), l, aZ0, false, a2f[0], a2f[1], a2f[2], a2f[3]);
    rit_hh(S0, srcIH(PIHF, w + 32), l, aZ0, false, a2f[4], a2f[5], a2f[6], a2f[7]);
    rit_ih(S1, srcIH(PIHF, w + 40), l, cc, g4, Ab, aZ1);
    rit_hh(S2, srcHL(PHHF, w + 32), l, aZ1, false, a2f[0], a2f[1], a2f[2], a2f[3]);
    rit_hh(S3, srcHH(PHHF, w + 32), l, aZ1, false, a2f[4], a2f[5], a2f[6], a2f[7]);
    rit_ih(S0, srcHL(PHHF, w + 40), l, cc, g4, Ab, aI0);
    rit_ih(S1, srcHH(PHHF, w + 40), l, cc, g4, Ab, aI1);
    // last 4 issues feed NEXT step's reads of these slots (order it2,it3,it0,it1):
    rit_hh(S2, srcHH(PHHF, w),      l, aH0, true,  a2f[0], a2f[1], a2f[2], a2f[3]);
    rit_hh(S3, srcIH(PIHF, w + 8),  l, aH0, false, a2f[4], a2f[5], a2f[6], a2f[7]);
    rit_hh(S0, srcIH(PIHF, w),      l, aH1, true,  a2f[0], a2f[1], a2f[2], a2f[3]);
    rit_hh(S1, srcHL(PHHF, w),      l, aH1, false, a2f[4], a2f[5], a2f[6], a2f[7]);

    if (t < 99){
      bf16x8 a = ldF(X0b[(t + 1) & 1], cc, g4 * 8, RB_X);
      f32x4 xa = MFMA(a, bEE, zf, 0, 0, 0);
      #pragma unroll
      for (int q = 0; q < 4; ++q)
        stBf(A1[(t + 1) & 1], g4 * 4 + q, u0, RB_A1, fmaxf(xa[q] + beer, 0.f));
    }
    if (t < 98) stage_x(x, s0, t + 2, X0b[t & 1], tid);
    __syncthreads();   // all ring/A reads done before combine writes

    // lane-local combine: unit u0 and u1, samples g4*4+q
    #pragma unroll
    for (int q = 0; q < 4; ++q){
      float r  = sigm(aR0[q] + br0);
      float zz = sigm(aZ0[q] + bz0);
      float n  = tanh_f(aI0[q] + bi0 + r * (aH0[q] + bh0));
      float h  = (1.f - zz) * n + zz * hr[q];
      hr[q] = h;
      stBf(A2s, g4 * 4 + q, u0, RB_A2, h);
      float r1 = sigm(aR1[q] + br1);
      float z1 = sigm(aZ1[q] + bz1);
      float n1 = tanh_f(aI1[q] + bi1 + r1 * (aH1[q] + bh1));
      float h1v = (1.f - z1) * n1 + z1 * hr[4 + q];
      hr[4 + q] = h1v;
      stBf(A2s, g4 * 4 + q, u1, RB_A2, h1v);
    }
    __syncthreads();   // combine writes visible before next ring
  }

  asm volatile("s_waitcnt vmcnt(0)" ::: "memory");   // drain stale prefetch

  // ---------------- backward cell (h0=0), lane-local ----------------
  {
    bf16x8 b1f[4];
    #pragma unroll
    for (int kt = 0; kt < 4; ++kt) b1f[kt] = ldF(A1[1], cc, kt * 32 + g4 * 8, RB_A1);
    #pragma unroll
    for (int j = 0; j < 2; ++j){
      f32x4 bR = zf, bZ = zf, bI = zf;
      #pragma unroll
      for (int kt = 0; kt < 4; ++kt){
        bR = MFMA(b1f[kt], gfrag(PIHB, w + 8*j,      4, kt, l), bR, 0,0,0);
        bZ = MFMA(b1f[kt], gfrag(PIHB, w + 16 + 8*j, 4, kt, l), bZ, 0,0,0);
        bI = MFMA(b1f[kt], gfrag(PIHB, w + 32 + 8*j, 4, kt, l), bI, 0,0,0);
      }
      const int uj = (j == 0) ? u0 : u1;
      const float brb = bih_b[uj] + bhh_b[uj];
      const float bzb = bih_b[256+uj] + bhh_b[256+uj];
      const float bib = bih_b[512+uj], bhb = bhh_b[512+uj];
      #pragma unroll
      for (int q = 0; q < 4; ++q){
        float r  = sigm(bR[q] + brb);
        float zz = sigm(bZ[q] + bzb);
        float n  = tanh_f(bI[q] + bib + r * bhb);
        stBf(HBb, g4 * 4 + q, uj, RB_A2, (1.f - zz) * n);
      }
    }
  }
  __syncthreads();

  // ---------------- stats = [h_fwd | h_bwd] @ W_enc + b_enc ----------------
  {
    f32x4 sa = zf;
    #pragma unroll
    for (int kt = 0; kt < 8; ++kt)
      sa = MFMA(ldF(A2s, cc, kt * 32 + g4 * 8, RB_A2), gfrag(PENC, w, 16, kt, l), sa, 0, 0, 0);
    #pragma unroll
    for (int kt = 8; kt < 16; ++kt)
      sa = MFMA(ldF(HBb, cc, (kt - 8) * 32 + g4 * 8, RB_A2), gfrag(PENC, w, 16, kt, l), sa, 0, 0, 0);
    const float be = b_enc[16 * w + cc];
    #pragma unroll
    for (int q = 0; q < 4; ++q)
      ST[(g4 * 4 + q) * 132 + 16 * w + cc] = sa[q] + be;
  }
  __syncthreads();

  // ---------------- z; write mu/logvar ----------------
  {
    const int s = tid >> 5, jj = (tid & 31) * 2;
    #pragma unroll
    for (int d = 0; d < 2; ++d){
      const int j = jj + d;
      float mu = ST[s * 132 + j], lv = ST[s * 132 + 64 + j];
      out[6553600u + (size_t)(s0 + s) * 64 + j] = mu;
      out[6684672u + (size_t)(s0 + s) * 64 + j] = lv;
      float zv = mu + __expf(0.5f * lv) * eps[(size_t)(s0 + s) * 64 + j];
      stBf(A1[0], s, j, RB_A1, zv);
    }
  }
  __syncthreads();

  // ---------------- h_dec0 = relu(z @ W_z2h + b) -> A2s + lane carry; dec biases ----------------
  #pragma unroll
  for (int j = 0; j < 2; ++j){
    const int g = w + 8 * j;
    f32x4 da = zf;
    #pragma unroll
    for (int kt = 0; kt < 2; ++kt)
      da = MFMA(ldF(A1[0], cc, kt * 32 + g4 * 8, RB_A1), gfrag(PZ2H, g, 2, kt, l), da, 0, 0, 0);
    const float bz = b_z2h[(j == 0) ? u0 : u1];
    #pragma unroll
    for (int q = 0; q < 4; ++q){
      float v = fmaxf(da[q] + bz, 0.f);
      hr[j * 4 + q] = v;
      stBf(A2s, g4 * 4 + q, (j == 0) ? u0 : u1, RB_A2, v);
    }
  }
  br0 = bih_d[u0] + bhh_d[u0];       br1 = bih_d[u1] + bhh_d[u1];
  bz0 = bih_d[256+u0] + bhh_d[256+u0]; bz1 = bih_d[256+u1] + bhh_d[256+u1];
  bi0 = bih_d[512+u0]; bi1 = bih_d[512+u1];
  bh0 = bhh_d[512+u0]; bh1 = bhh_d[512+u1];
  __syncthreads();

  const float bh2ir = (w < 4) ? b_h2i[16 * w + cc] : 0.f;
  const float bder  = (w >= 4) ? ((const float*)(ws + OFF_BDE))[16 * (w - 4) + cc] : 0.f;
  const float bdecr = (w == 2 || w == 3) ? b_dec[16 * (w - 2) + cc] : 0.f;

  // ---------------- hid0 (w<4), cur0 ----------------
  if (w < 4){
    f32x4 ha = zf;
    #pragma unroll
    for (int kt = 0; kt < 8; ++kt)
      ha = MFMA(ldF(A2s, cc, kt * 32 + g4 * 8, RB_A2), gfrag(PH2I, w, 8, kt, l), ha, 0, 0, 0);
    #pragma unroll
    for (int q = 0; q < 4; ++q)
      stBf(A1[0], g4 * 4 + q, 64 + 16 * w + cc, RB_A1, fmaxf(ha[q] + bh2ir, 0.f));
  }
  {
    const int s = tid >> 5, jj = (tid & 31) * 2;
    #pragma unroll
    for (int d = 0; d < 2; ++d)
      stBf(A1[0], s, jj + d, RB_A1, fmaxf(b_ed[jj + d], 0.f));
  }
  issue4(srcIH(PIHD, w), S0, l);
  issue4(srcHL(PHHD, w), S1, l);
  issue4(srcHH(PHHD, w), S2, l);
  issue4(srcIH(PIHD, w + 8), S3, l);
  __syncthreads();

  // ---------------- decoder: 100 steps ----------------
  for (int t = 0; t < 100; ++t){
    const char* Ab = A1[0];
    bf16x8 a2f[8];
    #pragma unroll
    for (int kt = 0; kt < 8; ++kt) a2f[kt] = ldF(A2s, cc, kt * 32 + g4 * 8, RB_A2);

    rit_ih(S0, srcHL(PHHD, w + 8),  l, cc, g4, Ab, aR0);
    rit_hh(S1, srcHH(PHHD, w + 8),  l, aR0, false, a2f[0], a2f[1], a2f[2], a2f[3]);
    rit_hh(S2, srcIH(PIHD, w + 16), l, aR0, false, a2f[4], a2f[5], a2f[6], a2f[7]);
    rit_ih(S3, srcHL(PHHD, w + 16), l, cc, g4, Ab, aR1);
    rit_hh(S0, srcHH(PHHD, w + 16), l, aR1, false, a2f[0], a2f[1], a2f[2], a2f[3]);
    rit_hh(S1, srcIH(PIHD, w + 24), l, aR1, false, a2f[4], a2f[5], a2f[6], a2f[7]);
    rit_ih(S2, srcHL(PHHD, w + 24), l, cc, g4, Ab, aZ0);
    rit_hh(S3, srcHH(PHHD, w + 24), l, aZ0, false, a2f[0], a2f[1], a2f[2], a2f[3]);
    rit_hh(S0, srcIH(PIHD, w + 32), l, aZ0, false, a2f[4], a2f[5], a2f[6], a2f[7]);
    rit_ih(S1, srcIH(PIHD, w + 40), l, cc, g4, Ab, aZ1);
    rit_hh(S2, srcHL(PHHD, w + 32), l, aZ1, false, a2f[0], a2f[1], a2f[2], a2f[3]);
    rit_hh(S3, srcHH(PHHD, w + 32), l, aZ1, false, a2f[4], a2f[5], a2f[6], a2f[7]);
    rit_ih(S0, srcHL(PHHD, w + 40), l, cc, g4, Ab, aI0);
    rit_ih(S1, srcHH(PHHD, w + 40), l, cc, g4, Ab, aI1);
    // last 4 issues feed NEXT step's reads (order it2,it3,it0,it1):
    rit_hh(S2, srcHH(PHHD, w),      l, aH0, true,  a2f[0], a2f[1], a2f[2], a2f[3]);
    rit_hh(S3, srcIH(PIHD, w + 8),  l, aH0, false, a2f[4], a2f[5], a2f[6], a2f[7]);
    rit_hh(S0, srcIH(PIHD, w),      l, aH1, true,  a2f[0], a2f[1], a2f[2], a2f[3]);
    rit_hh(S1, srcHL(PHHD, w),      l, aH1, false, a2f[4], a2f[5], a2f[6], a2f[7]);
    __syncthreads();

    // lane-local combine -> h2
    #pragma unroll
    for (int q = 0; q < 4; ++q){
      float r  = sigm(aR0[q] + br0);
      float zz = sigm(aZ0[q] + bz0);
      float n  = tanh_f(aI0[q] + bi0 + r * (aH0[q] + bh0));
      float h  = (1.f - zz) * n + zz * hr[q];
      hr[q] = h;
      stBf(A2s, g4 * 4 + q, u0, RB_A2, h);
      float r1 = sigm(aR1[q] + br1);
      float z1 = sigm(aZ1[q] + bz1);
      float n1 = tanh_f(aI1[q] + bi1 + r1 * (aH1[q] + bh1));
      float h1v = (1.f - z1) * n1 + z1 * hr[4 + q];
      hr[4 + q] = h1v;
      stBf(A2s, g4 * 4 + q, u1, RB_A2, h1v);
    }
    __syncthreads();

    // heads: w0-3 h2i -> A1 hi; w4-7 fused cur (Wde) -> A1 lo; w2-3 x_cur -> out
    {
      bf16x8 af[8];
      #pragma unroll
      for (int kt = 0; kt < 8; ++kt) af[kt] = ldF(A2s, cc, kt * 32 + g4 * 8, RB_A2);
      f32x4 hv = zf;
      if (w < 4){
        #pragma unroll
        for (int kt = 0; kt < 8; ++kt) hv = MFMA(af[kt], gfrag(PH2I, w, 8, kt, l), hv, 0, 0, 0);
        #pragma unroll
        for (int q = 0; q < 4; ++q)
          stBf(A1[0], g4 * 4 + q, 64 + 16 * w + cc, RB_A1, fmaxf(hv[q] + bh2ir, 0.f));
      } else {
        #pragma unroll
        for (int kt = 0; kt < 8; ++kt) hv = MFMA(af[kt], gfrag(PDE, w - 4, 8, kt, l), hv, 0, 0, 0);
        #pragma unroll
        for (int q = 0; q < 4; ++q)
          stBf(A1[0], g4 * 4 + q, 16 * (w - 4) + cc, RB_A1, fmaxf(hv[q] + bder, 0.f));
      }
      if (w == 2 || w == 3){
        f32x4 xc = zf;
        #pragma unroll
        for (int kt = 0; kt < 8; ++kt) xc = MFMA(af[kt], gfrag(PDEC, w - 2, 8, kt, l), xc, 0, 0, 0);
        #pragma unroll
        for (int q = 0; q < 4; ++q)
          out[(size_t)(s0 + g4 * 4 + q) * 3200 + t * 32 + 16 * (w - 2) + cc] = xc[q] + bdecr;
      }
    }
    __syncthreads();
  }
}

extern "C" void kernel_launch(void* const* d_in, const int* in_sizes, int n_in,
                              void* d_out, int out_size, void* d_ws, size_t ws_size,
                              hipStream_t stream)
{
  (void)in_sizes; (void)n_in; (void)out_size;
  if (ws_size < (size_t)WS_TOTAL) return;

  const float* x    = (const float*)d_in[0];
  const float* eps  = (const float*)d_in[1];
  const float* Wee  = (const float*)d_in[2];
  const float* bee  = (const float*)d_in[3];
  const float* Wihf = (const float*)d_in[4];
  const float* Whhf = (const float*)d_in[5];
  const float* bihf = (const float*)d_in[6];
  const float* bhhf = (const float*)d_in[7];
  const float* Wihb = (const float*)d_in[8];
  const float* bihb = (const float*)d_in[10];
  const float* bhhb = (const float*)d_in[11];
  const float* Wenc = (const float*)d_in[12];
  const float* benc = (const float*)d_in[13];
  const float* Wz2h = (const float*)d_in[14];
  const float* bz2h = (const float*)d_in[15];
  const float* Wh2i = (const float*)d_in[16];
  const float* bh2i = (const float*)d_in[17];
  const float* Wihd = (const float*)d_in[18];
  const float* Whhd = (const float*)d_in[19];
  const float* bihd = (const float*)d_in[20];
  const float* bhhd = (const float*)d_in[21];
  const float* Wed  = (const float*)d_in[22];
  const float* bed  = (const float*)d_in[23];
  const float* Wdec = (const float*)d_in[24];
  const float* bdec = (const float*)d_in[25];
  char* ws = (char*)d_ws;

  pack_all<<<3193, 256, 0, stream>>>(Wihf, Whhf, Wihb, Wihd, Whhd, Wenc, Wz2h, Wh2i,
                                     Wdec, Wee, Wed, bed, bdec, ws);
  vae_main<<<128, 512, 0, stream>>>(x, eps, bee, bihf, bhhf, bihb, bhhb, bihd, bhhd,
                                    benc, bz2h, bh2i, bed, bdec, ws, (float*)d_out);
}

// Round 15
// 1187.652 us; speedup vs baseline: 2.4471x; 1.3427x over previous
//
#include <hip/hip_runtime.h>
#include <hip/hip_bf16.h>

typedef __bf16 bf16x8 __attribute__((ext_vector_type(8)));
typedef float  f32x4  __attribute__((ext_vector_type(4)));
typedef unsigned short u16;

#define DEVI __device__ __forceinline__
#define MFMA __builtin_amdgcn_mfma_f32_16x16x32_bf16

DEVI u16 f2bf(float f){
  unsigned u = __builtin_bit_cast(unsigned, f);
  u += 0x7fffu + ((u >> 16) & 1u);
  return (u16)(u >> 16);
}
DEVI float bf2f(u16 h){
  unsigned u = ((unsigned)h) << 16;
  return __builtin_bit_cast(float, u);
}

// ---- ws layout (bytes); bf16 MFMA B-fragments, identity column order ----
enum : int {
  OFF_IHF = 0,                       // Wih_f: (128,768)  KT=4
  OFF_HHF = 196608,                  // Whh_f: (256,768)  KT=8
  OFF_IHB = 589824,                  // Wih_b: (128,768)  KT=4
  OFF_IHD = 786432,                  // Wih_d: (128,768)  KT=4
  OFF_HHD = 983040,                  // Whh_d: (256,768)  KT=8
  OFF_ENC = 1376256,                 // W_enc: (512,128)  KT=16
  OFF_Z2H = 1507328,                 // W_z2h: (64,256)   KT=2
  OFF_H2I = 1540096,                 // W_h2i: (256,64)   KT=8
  OFF_DEC = 1572864,                 // W_dec: (256,32)   KT=8
  OFF_EE  = 1589248,                 // W_ee : (32,128)   KT=1
  OFF_ED  = 1597440,                 // W_ed : (32,64)    KT=1 (unused by main)
  OFF_DE  = 1601536,                 // Wde = Wdec@Wed: (256,64) KT=8
  OFF_BDE = 1634304,                 // bde = bdec@Wed + bed: 64 f32
  WS_TOTAL = 1634560
};

DEVI void packseg(const float* __restrict__ W, u16* __restrict__ dst, int li, int N, int KT){
  int j = li & 7, l = (li >> 3) & 63, f = li >> 9;
  int kt = f % KT, ntg = f / KT;
  int k = kt * 32 + ((l >> 4) << 3) + j;
  int col = (ntg << 4) + (l & 15);
  dst[li] = f2bf(W[k * N + col]);
}

__global__ void pack_all(const float* Wihf, const float* Whhf, const float* Wihb,
                         const float* Wihd, const float* Whhd, const float* Wenc,
                         const float* Wz2h, const float* Wh2i, const float* Wdec,
                         const float* Wee,  const float* Wed,
                         const float* bed,  const float* bdec, char* ws)
{
  int idx = blockIdx.x * 256 + threadIdx.x;
  if (idx < 98304) { packseg(Wihf, (u16*)(ws+OFF_IHF), idx, 768, 4); return; } idx -= 98304;
  if (idx < 196608){ packseg(Whhf, (u16*)(ws+OFF_HHF), idx, 768, 8); return; } idx -= 196608;
  if (idx < 98304) { packseg(Wihb, (u16*)(ws+OFF_IHB), idx, 768, 4); return; } idx -= 98304;
  if (idx < 98304) { packseg(Wihd, (u16*)(ws+OFF_IHD), idx, 768, 4); return; } idx -= 98304;
  if (idx < 196608){ packseg(Whhd, (u16*)(ws+OFF_HHD), idx, 768, 8); return; } idx -= 196608;
  if (idx < 65536) { packseg(Wenc, (u16*)(ws+OFF_ENC), idx, 128, 16); return; } idx -= 65536;
  if (idx < 16384) { packseg(Wz2h, (u16*)(ws+OFF_Z2H), idx, 256, 2); return; } idx -= 16384;
  if (idx < 16384) { packseg(Wh2i, (u16*)(ws+OFF_H2I), idx, 64, 8); return; } idx -= 16384;
  if (idx < 8192)  { packseg(Wdec, (u16*)(ws+OFF_DEC), idx, 32, 8); return; } idx -= 8192;
  if (idx < 4096)  { packseg(Wee,  (u16*)(ws+OFF_EE),  idx, 128, 1); return; } idx -= 4096;
  if (idx < 2048)  { packseg(Wed,  (u16*)(ws+OFF_ED),  idx, 64, 1); return; } idx -= 2048;
  if (idx < 16384){
    int j = idx & 7, l = (idx >> 3) & 63, f = idx >> 9;
    int kt = f & 7, ntg = f >> 3;
    int k = kt * 32 + ((l >> 4) << 3) + j;
    int col = (ntg << 4) + (l & 15);
    float acc = 0.f;
    for (int m = 0; m < 32; ++m) acc += Wdec[k*32 + m] * Wed[m*64 + col];
    ((u16*)(ws+OFF_DE))[idx] = f2bf(acc);
    return;
  } idx -= 16384;
  if (idx < 64){
    float acc = bed[idx];
    for (int m = 0; m < 32; ++m) acc += bdec[m] * Wed[m*64 + idx];
    ((float*)(ws+OFF_BDE))[idx] = acc;
  }
}

// ---- LDS geometry ----
enum : int { RB_A1 = 272, RB_A2 = 528, RB_X = 80 };

DEVI bf16x8 ldF(const char* buf, int row, int kElem, int rowB){
  return *(const bf16x8*)(buf + row * rowB + kElem * 2);
}
DEVI void stBf(char* buf, int row, int col, int rowB, float v){
  *(u16*)(buf + row * rowB + col * 2) = f2bf(v);
}
DEVI bf16x8 gfrag(const u16* P, int ntg, int KT, int kt, int l){
  return *(const bf16x8*)(P + ((size_t)(ntg * KT + kt) * 64 + l) * 8);
}

DEVI float sigm(float x){ return 1.0f / (1.0f + __expf(-x)); }
DEVI float tanh_f(float x){ return 1.0f - 2.0f / (1.0f + __expf(2.0f * x)); }

DEVI void stage_x(const float* __restrict__ xg, int s0, int t, char* Xb, int tid){
  if (tid < 256){
    int s = tid >> 4, d0 = (tid & 15) * 2;
    float2 v = *(const float2*)(xg + (size_t)(s0 + s) * 3200 + t * 32 + d0);
    unsigned pk = (unsigned)f2bf(v.x) | ((unsigned)f2bf(v.y) << 16);
    *(unsigned*)(Xb + s * RB_X + d0 * 2) = pk;
  }
}

// ---- gate evaluators: weights stream global(L2)->VGPR directly ----
// r/z gate: ih (4 frags, A from A1 LDS) + hh (8 frags, A from a2f regs)
DEVI f32x4 gate_rz(const u16* PI, const u16* PH, int G, int l, int cc, int g4,
                   const char* Ab, const bf16x8 a2f[8]){
  bf16x8 w0 = gfrag(PI, G, 4, 0, l), w1 = gfrag(PI, G, 4, 1, l);
  bf16x8 w2 = gfrag(PI, G, 4, 2, l), w3 = gfrag(PI, G, 4, 3, l);
  bf16x8 a0 = ldF(Ab, cc, 0  + g4 * 8, RB_A1);
  bf16x8 a1 = ldF(Ab, cc, 32 + g4 * 8, RB_A1);
  bf16x8 a2 = ldF(Ab, cc, 64 + g4 * 8, RB_A1);
  bf16x8 a3 = ldF(Ab, cc, 96 + g4 * 8, RB_A1);
  f32x4 acc = {0.f, 0.f, 0.f, 0.f};
  acc = MFMA(a0, w0, acc, 0,0,0); acc = MFMA(a1, w1, acc, 0,0,0);
  acc = MFMA(a2, w2, acc, 0,0,0); acc = MFMA(a3, w3, acc, 0,0,0);
  bf16x8 h0 = gfrag(PH, G, 8, 0, l), h1 = gfrag(PH, G, 8, 1, l);
  bf16x8 h2 = gfrag(PH, G, 8, 2, l), h3 = gfrag(PH, G, 8, 3, l);
  acc = MFMA(a2f[0], h0, acc, 0,0,0); acc = MFMA(a2f[1], h1, acc, 0,0,0);
  acc = MFMA(a2f[2], h2, acc, 0,0,0); acc = MFMA(a2f[3], h3, acc, 0,0,0);
  bf16x8 h4 = gfrag(PH, G, 8, 4, l), h5 = gfrag(PH, G, 8, 5, l);
  bf16x8 h6 = gfrag(PH, G, 8, 6, l), h7 = gfrag(PH, G, 8, 7, l);
  acc = MFMA(a2f[4], h4, acc, 0,0,0); acc = MFMA(a2f[5], h5, acc, 0,0,0);
  acc = MFMA(a2f[6], h6, acc, 0,0,0); acc = MFMA(a2f[7], h7, acc, 0,0,0);
  return acc;
}
// in gate: ih only
DEVI f32x4 gate_i(const u16* PI, int G, int l, int cc, int g4, const char* Ab){
  bf16x8 w0 = gfrag(PI, G, 4, 0, l), w1 = gfrag(PI, G, 4, 1, l);
  bf16x8 w2 = gfrag(PI, G, 4, 2, l), w3 = gfrag(PI, G, 4, 3, l);
  bf16x8 a0 = ldF(Ab, cc, 0  + g4 * 8, RB_A1);
  bf16x8 a1 = ldF(Ab, cc, 32 + g4 * 8, RB_A1);
  bf16x8 a2 = ldF(Ab, cc, 64 + g4 * 8, RB_A1);
  bf16x8 a3 = ldF(Ab, cc, 96 + g4 * 8, RB_A1);
  f32x4 acc = {0.f, 0.f, 0.f, 0.f};
  acc = MFMA(a0, w0, acc, 0,0,0); acc = MFMA(a1, w1, acc, 0,0,0);
  acc = MFMA(a2, w2, acc, 0,0,0); acc = MFMA(a3, w3, acc, 0,0,0);
  return acc;
}
// hn gate: hh only
DEVI f32x4 gate_h(const u16* PH, int G, int l, const bf16x8 a2f[8]){
  bf16x8 h0 = gfrag(PH, G, 8, 0, l), h1 = gfrag(PH, G, 8, 1, l);
  bf16x8 h2 = gfrag(PH, G, 8, 2, l), h3 = gfrag(PH, G, 8, 3, l);
  f32x4 acc = {0.f, 0.f, 0.f, 0.f};
  acc = MFMA(a2f[0], h0, acc, 0,0,0); acc = MFMA(a2f[1], h1, acc, 0,0,0);
  acc = MFMA(a2f[2], h2, acc, 0,0,0); acc = MFMA(a2f[3], h3, acc, 0,0,0);
  bf16x8 h4 = gfrag(PH, G, 8, 4, l), h5 = gfrag(PH, G, 8, 5, l);
  bf16x8 h6 = gfrag(PH, G, 8, 6, l), h7 = gfrag(PH, G, 8, 7, l);
  acc = MFMA(a2f[4], h4, acc, 0,0,0); acc = MFMA(a2f[5], h5, acc, 0,0,0);
  acc = MFMA(a2f[6], h6, acc, 0,0,0); acc = MFMA(a2f[7], h7, acc, 0,0,0);
  return acc;
}

// raw barrier: make LDS writes visible without draining vmcnt
DEVI void lbar(){
  asm volatile("s_waitcnt lgkmcnt(0)" ::: "memory");
  __builtin_amdgcn_s_barrier();
}

// 128 blocks x 512 threads (8 waves), M=16, 1 block/CU (PAD pins LDS).
// Wave w owns units u0=16w+(l&15), u1=u0+128; lane-local GRU combine.
// Weights stream L2->VGPR directly (no LDS staging); j=0 fully combined
// before j=1 to cap accumulator registers at 16.
__global__ __launch_bounds__(512, 1) void vae_main(
    const float* __restrict__ x, const float* __restrict__ eps,
    const float* __restrict__ b_ee,
    const float* __restrict__ bih_f, const float* __restrict__ bhh_f,
    const float* __restrict__ bih_b, const float* __restrict__ bhh_b,
    const float* __restrict__ bih_d, const float* __restrict__ bhh_d,
    const float* __restrict__ b_enc, const float* __restrict__ b_z2h,
    const float* __restrict__ b_h2i, const float* __restrict__ b_ed,
    const float* __restrict__ b_dec,
    const char* __restrict__ ws, float* __restrict__ out)
{
  __shared__ __align__(16) char A1[2][16 * RB_A1]; // 8704
  __shared__ __align__(16) char A2s[16 * RB_A2];   // 8448
  __shared__ __align__(16) char HBb[16 * RB_A2];   // 8448
  __shared__ __align__(16) char X0b[2][16 * RB_X]; // 2560
  __shared__ float ST[16 * 132];                   // 8448
  __shared__ char PAD[94208];                      // occupancy pin: 1 block/CU

  const int tid = threadIdx.x;
  const int l = tid & 63;
  const int w = tid >> 6;       // wave 0..7
  const int cc = l & 15;
  const int g4 = l >> 4;
  const int s0 = blockIdx.x * 16;

  if (tid == 0) PAD[0] = 1;

  const u16* PIHF = (const u16*)(ws + OFF_IHF);
  const u16* PHHF = (const u16*)(ws + OFF_HHF);
  const u16* PIHB = (const u16*)(ws + OFF_IHB);
  const u16* PIHD = (const u16*)(ws + OFF_IHD);
  const u16* PHHD = (const u16*)(ws + OFF_HHD);
  const u16* PENC = (const u16*)(ws + OFF_ENC);
  const u16* PZ2H = (const u16*)(ws + OFF_Z2H);
  const u16* PH2I = (const u16*)(ws + OFF_H2I);
  const u16* PDEC = (const u16*)(ws + OFF_DEC);
  const u16* PEE  = (const u16*)(ws + OFF_EE);
  const u16* PDE  = (const u16*)(ws + OFF_DE);

  const f32x4 zf = {0.f, 0.f, 0.f, 0.f};

  // lane-local unit ids and gate biases (encoder set now)
  const int u0 = 16 * w + cc, u1 = u0 + 128;
  float brj[2], bzj[2], bij[2], bhj[2];
  brj[0] = bih_f[u0] + bhh_f[u0];         brj[1] = bih_f[u1] + bhh_f[u1];
  bzj[0] = bih_f[256+u0] + bhh_f[256+u0]; bzj[1] = bih_f[256+u1] + bhh_f[256+u1];
  bij[0] = bih_f[512+u0];                 bij[1] = bih_f[512+u1];
  bhj[0] = bhh_f[512+u0];                 bhj[1] = bhh_f[512+u1];
  const float beer = b_ee[u0];
  const bf16x8 bEE = gfrag(PEE, w, 1, 0, l);

  float hr[8];
  #pragma unroll
  for (int i = 0; i < 8; ++i) hr[i] = 0.f;

  // ---------------- prologue ----------------
  stage_x(x, s0, 0, X0b[0], tid);
  for (int i = tid; i < 16 * RB_A2 / 4; i += 512) ((unsigned*)A2s)[i] = 0u;
  __syncthreads();
  {
    bf16x8 a = ldF(X0b[0], cc, g4 * 8, RB_X);
    f32x4 xa = MFMA(a, bEE, zf, 0, 0, 0);
    #pragma unroll
    for (int q = 0; q < 4; ++q)
      stBf(A1[0], g4 * 4 + q, u0, RB_A1, fmaxf(xa[q] + beer, 0.f));
  }
  stage_x(x, s0, 1, X0b[1], tid);
  __syncthreads();

  // ---------------- encoder: 100 steps ----------------
  for (int t = 0; t < 100; ++t){
    const char* Ab = A1[t & 1];
    bf16x8 a2f[8];
    #pragma unroll
    for (int kt = 0; kt < 8; ++kt) a2f[kt] = ldF(A2s, cc, kt * 32 + g4 * 8, RB_A2);
    lbar();   // all waves have h in regs before any combine write

    #pragma unroll
    for (int j = 0; j < 2; ++j){
      f32x4 aR = gate_rz(PIHF, PHHF, w + 8*j,      l, cc, g4, Ab, a2f);
      f32x4 aZ = gate_rz(PIHF, PHHF, w + 16 + 8*j, l, cc, g4, Ab, a2f);
      f32x4 aI = gate_i (PIHF,       w + 32 + 8*j, l, cc, g4, Ab);
      f32x4 aH = gate_h (PHHF,       w + 32 + 8*j, l, a2f);
      const int uj = (j == 0) ? u0 : u1;
      #pragma unroll
      for (int q = 0; q < 4; ++q){
        float r  = sigm(aR[q] + brj[j]);
        float zz = sigm(aZ[q] + bzj[j]);
        float n  = tanh_f(aI[q] + bij[j] + r * (aH[q] + bhj[j]));
        float h  = (1.f - zz) * n + zz * hr[j * 4 + q];
        hr[j * 4 + q] = h;
        stBf(A2s, g4 * 4 + q, uj, RB_A2, h);
      }
    }

    if (t < 99){
      bf16x8 a = ldF(X0b[(t + 1) & 1], cc, g4 * 8, RB_X);
      f32x4 xa = MFMA(a, bEE, zf, 0, 0, 0);
      #pragma unroll
      for (int q = 0; q < 4; ++q)
        stBf(A1[(t + 1) & 1], g4 * 4 + q, u0, RB_A1, fmaxf(xa[q] + beer, 0.f));
    }
    if (t < 98) stage_x(x, s0, t + 2, X0b[t & 1], tid);
    lbar();   // combine/xe writes visible before next step's reads
  }

  // ---------------- backward cell (h0=0), lane-local ----------------
  {
    bf16x8 b1f[4];
    #pragma unroll
    for (int kt = 0; kt < 4; ++kt) b1f[kt] = ldF(A1[1], cc, kt * 32 + g4 * 8, RB_A1);
    #pragma unroll
    for (int j = 0; j < 2; ++j){
      f32x4 bR = zf, bZ = zf, bI = zf;
      #pragma unroll
      for (int kt = 0; kt < 4; ++kt){
        bR = MFMA(b1f[kt], gfrag(PIHB, w + 8*j,      4, kt, l), bR, 0,0,0);
        bZ = MFMA(b1f[kt], gfrag(PIHB, w + 16 + 8*j, 4, kt, l), bZ, 0,0,0);
        bI = MFMA(b1f[kt], gfrag(PIHB, w + 32 + 8*j, 4, kt, l), bI, 0,0,0);
      }
      const int uj = (j == 0) ? u0 : u1;
      const float brb = bih_b[uj] + bhh_b[uj];
      const float bzb = bih_b[256+uj] + bhh_b[256+uj];
      const float bib = bih_b[512+uj], bhb = bhh_b[512+uj];
      #pragma unroll
      for (int q = 0; q < 4; ++q){
        float r  = sigm(bR[q] + brb);
        float zz = sigm(bZ[q] + bzb);
        float n  = tanh_f(bI[q] + bib + r * bhb);
        stBf(HBb, g4 * 4 + q, uj, RB_A2, (1.f - zz) * n);
      }
    }
  }
  __syncthreads();

  // ---------------- stats = [h_fwd | h_bwd] @ W_enc + b_enc ----------------
  {
    f32x4 sa = zf;
    #pragma unroll
    for (int kt = 0; kt < 8; ++kt)
      sa = MFMA(ldF(A2s, cc, kt * 32 + g4 * 8, RB_A2), gfrag(PENC, w, 16, kt, l), sa, 0, 0, 0);
    #pragma unroll
    for (int kt = 8; kt < 16; ++kt)
      sa = MFMA(ldF(HBb, cc, (kt - 8) * 32 + g4 * 8, RB_A2), gfrag(PENC, w, 16, kt, l), sa, 0, 0, 0);
    const float be = b_enc[16 * w + cc];
    #pragma unroll
    for (int q = 0; q < 4; ++q)
      ST[(g4 * 4 + q) * 132 + 16 * w + cc] = sa[q] + be;
  }
  __syncthreads();

  // ---------------- z; write mu/logvar ----------------
  {
    const int s = tid >> 5, jj = (tid & 31) * 2;
    #pragma unroll
    for (int d = 0; d < 2; ++d){
      const int j = jj + d;
      float mu = ST[s * 132 + j], lv = ST[s * 132 + 64 + j];
      out[6553600u + (size_t)(s0 + s) * 64 + j] = mu;
      out[6684672u + (size_t)(s0 + s) * 64 + j] = lv;
      float zv = mu + __expf(0.5f * lv) * eps[(size_t)(s0 + s) * 64 + j];
      stBf(A1[0], s, j, RB_A1, zv);
    }
  }
  __syncthreads();

  // ---------------- h_dec0 = relu(z @ W_z2h + b) -> A2s + lane carry; dec biases ----------------
  #pragma unroll
  for (int j = 0; j < 2; ++j){
    const int g = w + 8 * j;
    f32x4 da = zf;
    #pragma unroll
    for (int kt = 0; kt < 2; ++kt)
      da = MFMA(ldF(A1[0], cc, kt * 32 + g4 * 8, RB_A1), gfrag(PZ2H, g, 2, kt, l), da, 0, 0, 0);
    const float bz = b_z2h[(j == 0) ? u0 : u1];
    #pragma unroll
    for (int q = 0; q < 4; ++q){
      float v = fmaxf(da[q] + bz, 0.f);
      hr[j * 4 + q] = v;
      stBf(A2s, g4 * 4 + q, (j == 0) ? u0 : u1, RB_A2, v);
    }
  }
  brj[0] = bih_d[u0] + bhh_d[u0];         brj[1] = bih_d[u1] + bhh_d[u1];
  bzj[0] = bih_d[256+u0] + bhh_d[256+u0]; bzj[1] = bih_d[256+u1] + bhh_d[256+u1];
  bij[0] = bih_d[512+u0];                 bij[1] = bih_d[512+u1];
  bhj[0] = bhh_d[512+u0];                 bhj[1] = bhh_d[512+u1];
  __syncthreads();

  const float bh2ir = (w < 4) ? b_h2i[16 * w + cc] : 0.f;
  const float bder  = (w >= 4) ? ((const float*)(ws + OFF_BDE))[16 * (w - 4) + cc] : 0.f;
  const float bdecr = (w == 2 || w == 3) ? b_dec[16 * (w - 2) + cc] : 0.f;

  // ---------------- hid0 (w<4), cur0 ----------------
  if (w < 4){
    f32x4 ha = zf;
    #pragma unroll
    for (int kt = 0; kt < 8; ++kt)
      ha = MFMA(ldF(A2s, cc, kt * 32 + g4 * 8, RB_A2), gfrag(PH2I, w, 8, kt, l), ha, 0, 0, 0);
    #pragma unroll
    for (int q = 0; q < 4; ++q)
      stBf(A1[0], g4 * 4 + q, 64 + 16 * w + cc, RB_A1, fmaxf(ha[q] + bh2ir, 0.f));
  }
  {
    const int s = tid >> 5, jj = (tid & 31) * 2;
    #pragma unroll
    for (int d = 0; d < 2; ++d)
      stBf(A1[0], s, jj + d, RB_A1, fmaxf(b_ed[jj + d], 0.f));
  }
  __syncthreads();

  // ---------------- decoder: 100 steps ----------------
  for (int t = 0; t < 100; ++t){
    const char* Ab = A1[0];
    bf16x8 a2f[8];
    #pragma unroll
    for (int kt = 0; kt < 8; ++kt) a2f[kt] = ldF(A2s, cc, kt * 32 + g4 * 8, RB_A2);
    lbar();

    #pragma unroll
    for (int j = 0; j < 2; ++j){
      f32x4 aR = gate_rz(PIHD, PHHD, w + 8*j,      l, cc, g4, Ab, a2f);
      f32x4 aZ = gate_rz(PIHD, PHHD, w + 16 + 8*j, l, cc, g4, Ab, a2f);
      f32x4 aI = gate_i (PIHD,       w + 32 + 8*j, l, cc, g4, Ab);
      f32x4 aH = gate_h (PHHD,       w + 32 + 8*j, l, a2f);
      const int uj = (j == 0) ? u0 : u1;
      #pragma unroll
      for (int q = 0; q < 4; ++q){
        float r  = sigm(aR[q] + brj[j]);
        float zz = sigm(aZ[q] + bzj[j]);
        float n  = tanh_f(aI[q] + bij[j] + r * (aH[q] + bhj[j]));
        float h  = (1.f - zz) * n + zz * hr[j * 4 + q];
        hr[j * 4 + q] = h;
        stBf(A2s, g4 * 4 + q, uj, RB_A2, h);
      }
    }
    lbar();   // h2 visible

    // heads: w0-3 h2i -> A1 hi; w4-7 fused cur (Wde) -> A1 lo; w2-3 x_cur -> out
    {
      bf16x8 af[8];
      #pragma unroll
      for (int kt = 0; kt < 8; ++kt) af[kt] = ldF(A2s, cc, kt * 32 + g4 * 8, RB_A2);
      f32x4 hv = zf;
      if (w < 4){
        #pragma unroll
        for (int kt = 0; kt < 8; ++kt) hv = MFMA(af[kt], gfrag(PH2I, w, 8, kt, l), hv, 0, 0, 0);
        #pragma unroll
        for (int q = 0; q < 4; ++q)
          stBf(A1[0], g4 * 4 + q, 64 + 16 * w + cc, RB_A1, fmaxf(hv[q] + bh2ir, 0.f));
      } else {
        #pragma unroll
        for (int kt = 0; kt < 8; ++kt) hv = MFMA(af[kt], gfrag(PDE, w - 4, 8, kt, l), hv, 0, 0, 0);
        #pragma unroll
        for (int q = 0; q < 4; ++q)
          stBf(A1[0], g4 * 4 + q, 16 * (w - 4) + cc, RB_A1, fmaxf(hv[q] + bder, 0.f));
      }
      if (w == 2 || w == 3){
        f32x4 xc = zf;
        #pragma unroll
        for (int kt = 0; kt < 8; ++kt) xc = MFMA(af[kt], gfrag(PDEC, w - 2, 8, kt, l), xc, 0, 0, 0);
        #pragma unroll
        for (int q = 0; q < 4; ++q)
          out[(size_t)(s0 + g4 * 4 + q) * 3200 + t * 32 + 16 * (w - 2) + cc] = xc[q] + bdecr;
      }
    }
    lbar();   // A1 inp writes visible before next step's gate reads
  }
}

extern "C" void kernel_launch(void* const* d_in, const int* in_sizes, int n_in,
                              void* d_out, int out_size, void* d_ws, size_t ws_size,
                              hipStream_t stream)
{
  (void)in_sizes; (void)n_in; (void)out_size;
  if (ws_size < (size_t)WS_TOTAL) return;

  const float* x    = (const float*)d_in[0];
  const float* eps  = (const float*)d_in[1];
  const float* Wee  = (const float*)d_in[2];
  const float* bee  = (const float*)d_in[3];
  const float* Wihf = (const float*)d_in[4];
  const float* Whhf = (const float*)d_in[5];
  const float* bihf = (const float*)d_in[6];
  const float* bhhf = (const float*)d_in[7];
  const float* Wihb = (const float*)d_in[8];
  const float* bihb = (const float*)d_in[10];
  const float* bhhb = (const float*)d_in[11];
  const float* Wenc = (const float*)d_in[12];
  const float* benc = (const float*)d_in[13];
  const float* Wz2h = (const float*)d_in[14];
  const float* bz2h = (const float*)d_in[15];
  const float* Wh2i = (const float*)d_in[16];
  const float* bh2i = (const float*)d_in[17];
  const float* Wihd = (const float*)d_in[18];
  const float* Whhd = (const float*)d_in[19];
  const float* bihd = (const float*)d_in[20];
  const float* bhhd = (const float*)d_in[21];
  const float* Wed  = (const float*)d_in[22];
  const float* bed  = (const float*)d_in[23];
  const float* Wdec = (const float*)d_in[24];
  const float* bdec = (const float*)d_in[25];
  char* ws = (char*)d_ws;

  pack_all<<<3193, 256, 0, stream>>>(Wihf, Whhf, Wihb, Wihd, Whhd, Wenc, Wz2h, Wh2i,
                                     Wdec, Wee, Wed, bed, bdec, ws);
  vae_main<<<128, 512, 0, stream>>>(x, eps, bee, bihf, bhhf, bihb, bhhb, bihd, bhhd,
                                    benc, bz2h, bh2i, bed, bdec, ws, (float*)d_out);
}

// Round 16
// 1105.318 us; speedup vs baseline: 2.6294x; 1.0745x over previous
//
#include <hip/hip_runtime.h>
#include <hip/hip_bf16.h>

typedef __bf16 bf16x8 __attribute__((ext_vector_type(8)));
typedef float  f32x4  __attribute__((ext_vector_type(4)));
typedef unsigned short u16;

#define DEVI __device__ __forceinline__
#define MFMA __builtin_amdgcn_mfma_f32_16x16x32_bf16

DEVI u16 f2bf(float f){
  unsigned u = __builtin_bit_cast(unsigned, f);
  u += 0x7fffu + ((u >> 16) & 1u);
  return (u16)(u >> 16);
}
DEVI float bf2f(u16 h){
  unsigned u = ((unsigned)h) << 16;
  return __builtin_bit_cast(float, u);
}

// ---- ws layout (bytes); bf16 MFMA B-fragments, identity column order ----
enum : int {
  OFF_IHF = 0,                       // Wih_f: (128,768)  KT=4
  OFF_HHF = 196608,                  // Whh_f: (256,768)  KT=8
  OFF_IHB = 589824,                  // Wih_b: (128,768)  KT=4
  OFF_IHD = 786432,                  // Wih_d: (128,768)  KT=4
  OFF_HHD = 983040,                  // Whh_d: (256,768)  KT=8
  OFF_ENC = 1376256,                 // W_enc: (512,128)  KT=16
  OFF_Z2H = 1507328,                 // W_z2h: (64,256)   KT=2
  OFF_H2I = 1540096,                 // W_h2i: (256,64)   KT=8
  OFF_DEC = 1572864,                 // W_dec: (256,32)   KT=8
  OFF_EE  = 1589248,                 // W_ee : (32,128)   KT=1
  OFF_ED  = 1597440,                 // W_ed : (32,64)    KT=1 (unused by main)
  OFF_DE  = 1601536,                 // Wde = Wdec@Wed: (256,64) KT=8
  OFF_BDE = 1634304,                 // bde = bdec@Wed + bed: 64 f32
  WS_TOTAL = 1634560
};

DEVI void packseg(const float* __restrict__ W, u16* __restrict__ dst, int li, int N, int KT){
  int j = li & 7, l = (li >> 3) & 63, f = li >> 9;
  int kt = f % KT, ntg = f / KT;
  int k = kt * 32 + ((l >> 4) << 3) + j;
  int col = (ntg << 4) + (l & 15);
  dst[li] = f2bf(W[k * N + col]);
}

__global__ void pack_all(const float* Wihf, const float* Whhf, const float* Wihb,
                         const float* Wihd, const float* Whhd, const float* Wenc,
                         const float* Wz2h, const float* Wh2i, const float* Wdec,
                         const float* Wee,  const float* Wed,
                         const float* bed,  const float* bdec, char* ws)
{
  int idx = blockIdx.x * 256 + threadIdx.x;
  if (idx < 98304) { packseg(Wihf, (u16*)(ws+OFF_IHF), idx, 768, 4); return; } idx -= 98304;
  if (idx < 196608){ packseg(Whhf, (u16*)(ws+OFF_HHF), idx, 768, 8); return; } idx -= 196608;
  if (idx < 98304) { packseg(Wihb, (u16*)(ws+OFF_IHB), idx, 768, 4); return; } idx -= 98304;
  if (idx < 98304) { packseg(Wihd, (u16*)(ws+OFF_IHD), idx, 768, 4); return; } idx -= 98304;
  if (idx < 196608){ packseg(Whhd, (u16*)(ws+OFF_HHD), idx, 768, 8); return; } idx -= 196608;
  if (idx < 65536) { packseg(Wenc, (u16*)(ws+OFF_ENC), idx, 128, 16); return; } idx -= 65536;
  if (idx < 16384) { packseg(Wz2h, (u16*)(ws+OFF_Z2H), idx, 256, 2); return; } idx -= 16384;
  if (idx < 16384) { packseg(Wh2i, (u16*)(ws+OFF_H2I), idx, 64, 8); return; } idx -= 16384;
  if (idx < 8192)  { packseg(Wdec, (u16*)(ws+OFF_DEC), idx, 32, 8); return; } idx -= 8192;
  if (idx < 4096)  { packseg(Wee,  (u16*)(ws+OFF_EE),  idx, 128, 1); return; } idx -= 4096;
  if (idx < 2048)  { packseg(Wed,  (u16*)(ws+OFF_ED),  idx, 64, 1); return; } idx -= 2048;
  if (idx < 16384){
    int j = idx & 7, l = (idx >> 3) & 63, f = idx >> 9;
    int kt = f & 7, ntg = f >> 3;
    int k = kt * 32 + ((l >> 4) << 3) + j;
    int col = (ntg << 4) + (l & 15);
    float acc = 0.f;
    for (int m = 0; m < 32; ++m) acc += Wdec[k*32 + m] * Wed[m*64 + col];
    ((u16*)(ws+OFF_DE))[idx] = f2bf(acc);
    return;
  } idx -= 16384;
  if (idx < 64){
    float acc = bed[idx];
    for (int m = 0; m < 32; ++m) acc += bdec[m] * Wed[m*64 + idx];
    ((float*)(ws+OFF_BDE))[idx] = acc;
  }
}

// ---- LDS geometry ----
enum : int { RB_A1 = 272, RB_A2 = 528, RB_X = 80 };

DEVI bf16x8 ldF(const char* buf, int row, int kElem, int rowB){
  return *(const bf16x8*)(buf + row * rowB + kElem * 2);
}
DEVI void stBf(char* buf, int row, int col, int rowB, float v){
  *(u16*)(buf + row * rowB + col * 2) = f2bf(v);
}
DEVI bf16x8 gfrag(const u16* P, int ntg, int KT, int kt, int l){
  return *(const bf16x8*)(P + ((size_t)(ntg * KT + kt) * 64 + l) * 8);
}

DEVI float sigm(float x){ return 1.0f / (1.0f + __expf(-x)); }
DEVI float tanh_f(float x){ return 1.0f - 2.0f / (1.0f + __expf(2.0f * x)); }

DEVI void stage_x(const float* __restrict__ xg, int s0, int t, char* Xb, int tid){
  if (tid < 256){
    int s = tid >> 4, d0 = (tid & 15) * 2;
    float2 v = *(const float2*)(xg + (size_t)(s0 + s) * 3200 + t * 32 + d0);
    unsigned pk = (unsigned)f2bf(v.x) | ((unsigned)f2bf(v.y) << 16);
    *(unsigned*)(Xb + s * RB_X + d0 * 2) = pk;
  }
}

// ---- async global->LDS DMA (cache fill; 16 B/lane, linear dest) ----
DEVI void dma16(const u16* g, char* lds){
  __builtin_amdgcn_global_load_lds(
      (const __attribute__((address_space(1))) unsigned*)(const void*)g,
      (__attribute__((address_space(3))) unsigned*)(void*)lds, 16, 0, 0);
}
DEVI void issue4(const u16* src, char* dst, int l){
  const u16* g0 = src + l * 8;
  dma16(g0, dst); dma16(g0 + 512, dst + 1024);
  dma16(g0 + 1024, dst + 2048); dma16(g0 + 1536, dst + 3072);
}
DEVI const u16* srcIH(const u16* PI, int ntg){ return PI + (size_t)ntg * 2048; }
DEVI const u16* srcHL(const u16* PH, int ntg){ return PH + (size_t)ntg * 4096; }
DEVI const u16* srcHH(const u16* PH, int ntg){ return PH + (size_t)ntg * 4096 + 2048; }
DEVI bf16x8 ldS(const char* base, int f, int l){
  return *(const bf16x8*)(base + f * 1024 + l * 16);
}

// fill one wave's 16-frag cache: 0-3 ih(g0), 4-11 hh(g0), 12-15 ih(g0+16)
DEVI void fill_cache(const u16* PI, const u16* PH, int w, int l, char* cwb){
  issue4(srcIH(PI, w),      cwb,         l);
  issue4(srcHL(PH, w),      cwb + 4096,  l);
  issue4(srcHH(PH, w),      cwb + 8192,  l);
  issue4(srcIH(PI, w + 16), cwb + 12288, l);
}

// ---- gate evaluators ----
// r/z gate streamed: ih (4 frags) + hh (8 frags) from L2
DEVI f32x4 gate_rz(const u16* PI, const u16* PH, int G, int l, int cc, int g4,
                   const char* Ab, const bf16x8 a2f[8]){
  bf16x8 w0 = gfrag(PI, G, 4, 0, l), w1 = gfrag(PI, G, 4, 1, l);
  bf16x8 w2 = gfrag(PI, G, 4, 2, l), w3 = gfrag(PI, G, 4, 3, l);
  bf16x8 a0 = ldF(Ab, cc, 0  + g4 * 8, RB_A1);
  bf16x8 a1 = ldF(Ab, cc, 32 + g4 * 8, RB_A1);
  bf16x8 a2 = ldF(Ab, cc, 64 + g4 * 8, RB_A1);
  bf16x8 a3 = ldF(Ab, cc, 96 + g4 * 8, RB_A1);
  f32x4 acc = {0.f, 0.f, 0.f, 0.f};
  acc = MFMA(a0, w0, acc, 0,0,0); acc = MFMA(a1, w1, acc, 0,0,0);
  acc = MFMA(a2, w2, acc, 0,0,0); acc = MFMA(a3, w3, acc, 0,0,0);
  bf16x8 h0 = gfrag(PH, G, 8, 0, l), h1 = gfrag(PH, G, 8, 1, l);
  bf16x8 h2 = gfrag(PH, G, 8, 2, l), h3 = gfrag(PH, G, 8, 3, l);
  acc = MFMA(a2f[0], h0, acc, 0,0,0); acc = MFMA(a2f[1], h1, acc, 0,0,0);
  acc = MFMA(a2f[2], h2, acc, 0,0,0); acc = MFMA(a2f[3], h3, acc, 0,0,0);
  bf16x8 h4 = gfrag(PH, G, 8, 4, l), h5 = gfrag(PH, G, 8, 5, l);
  bf16x8 h6 = gfrag(PH, G, 8, 6, l), h7 = gfrag(PH, G, 8, 7, l);
  acc = MFMA(a2f[4], h4, acc, 0,0,0); acc = MFMA(a2f[5], h5, acc, 0,0,0);
  acc = MFMA(a2f[6], h6, acc, 0,0,0); acc = MFMA(a2f[7], h7, acc, 0,0,0);
  return acc;
}
// r gate from LDS cache (frags 0-11)
DEVI f32x4 gate_r_cached(const char* cwb, int l, int cc, int g4,
                         const char* Ab, const bf16x8 a2f[8]){
  bf16x8 a0 = ldF(Ab, cc, 0  + g4 * 8, RB_A1);
  bf16x8 a1 = ldF(Ab, cc, 32 + g4 * 8, RB_A1);
  bf16x8 a2 = ldF(Ab, cc, 64 + g4 * 8, RB_A1);
  bf16x8 a3 = ldF(Ab, cc, 96 + g4 * 8, RB_A1);
  f32x4 acc = {0.f, 0.f, 0.f, 0.f};
  acc = MFMA(a0, ldS(cwb, 0, l), acc, 0,0,0);
  acc = MFMA(a1, ldS(cwb, 1, l), acc, 0,0,0);
  acc = MFMA(a2, ldS(cwb, 2, l), acc, 0,0,0);
  acc = MFMA(a3, ldS(cwb, 3, l), acc, 0,0,0);
  #pragma unroll
  for (int kt = 0; kt < 8; ++kt)
    acc = MFMA(a2f[kt], ldS(cwb, 4 + kt, l), acc, 0,0,0);
  return acc;
}
// z gate: ih from cache (frags 12-15), hh streamed
DEVI f32x4 gate_z_cached(const char* cwb, const u16* PH, int G, int l, int cc,
                         int g4, const char* Ab, const bf16x8 a2f[8]){
  bf16x8 a0 = ldF(Ab, cc, 0  + g4 * 8, RB_A1);
  bf16x8 a1 = ldF(Ab, cc, 32 + g4 * 8, RB_A1);
  bf16x8 a2 = ldF(Ab, cc, 64 + g4 * 8, RB_A1);
  bf16x8 a3 = ldF(Ab, cc, 96 + g4 * 8, RB_A1);
  f32x4 acc = {0.f, 0.f, 0.f, 0.f};
  acc = MFMA(a0, ldS(cwb, 12, l), acc, 0,0,0);
  acc = MFMA(a1, ldS(cwb, 13, l), acc, 0,0,0);
  acc = MFMA(a2, ldS(cwb, 14, l), acc, 0,0,0);
  acc = MFMA(a3, ldS(cwb, 15, l), acc, 0,0,0);
  bf16x8 h0 = gfrag(PH, G, 8, 0, l), h1 = gfrag(PH, G, 8, 1, l);
  bf16x8 h2 = gfrag(PH, G, 8, 2, l), h3 = gfrag(PH, G, 8, 3, l);
  acc = MFMA(a2f[0], h0, acc, 0,0,0); acc = MFMA(a2f[1], h1, acc, 0,0,0);
  acc = MFMA(a2f[2], h2, acc, 0,0,0); acc = MFMA(a2f[3], h3, acc, 0,0,0);
  bf16x8 h4 = gfrag(PH, G, 8, 4, l), h5 = gfrag(PH, G, 8, 5, l);
  bf16x8 h6 = gfrag(PH, G, 8, 6, l), h7 = gfrag(PH, G, 8, 7, l);
  acc = MFMA(a2f[4], h4, acc, 0,0,0); acc = MFMA(a2f[5], h5, acc, 0,0,0);
  acc = MFMA(a2f[6], h6, acc, 0,0,0); acc = MFMA(a2f[7], h7, acc, 0,0,0);
  return acc;
}
// in gate: ih only (streamed)
DEVI f32x4 gate_i(const u16* PI, int G, int l, int cc, int g4, const char* Ab){
  bf16x8 w0 = gfrag(PI, G, 4, 0, l), w1 = gfrag(PI, G, 4, 1, l);
  bf16x8 w2 = gfrag(PI, G, 4, 2, l), w3 = gfrag(PI, G, 4, 3, l);
  bf16x8 a0 = ldF(Ab, cc, 0  + g4 * 8, RB_A1);
  bf16x8 a1 = ldF(Ab, cc, 32 + g4 * 8, RB_A1);
  bf16x8 a2 = ldF(Ab, cc, 64 + g4 * 8, RB_A1);
  bf16x8 a3 = ldF(Ab, cc, 96 + g4 * 8, RB_A1);
  f32x4 acc = {0.f, 0.f, 0.f, 0.f};
  acc = MFMA(a0, w0, acc, 0,0,0); acc = MFMA(a1, w1, acc, 0,0,0);
  acc = MFMA(a2, w2, acc, 0,0,0); acc = MFMA(a3, w3, acc, 0,0,0);
  return acc;
}
// hn gate: hh only (streamed)
DEVI f32x4 gate_h(const u16* PH, int G, int l, const bf16x8 a2f[8]){
  bf16x8 h0 = gfrag(PH, G, 8, 0, l), h1 = gfrag(PH, G, 8, 1, l);
  bf16x8 h2 = gfrag(PH, G, 8, 2, l), h3 = gfrag(PH, G, 8, 3, l);
  f32x4 acc = {0.f, 0.f, 0.f, 0.f};
  acc = MFMA(a2f[0], h0, acc, 0,0,0); acc = MFMA(a2f[1], h1, acc, 0,0,0);
  acc = MFMA(a2f[2], h2, acc, 0,0,0); acc = MFMA(a2f[3], h3, acc, 0,0,0);
  bf16x8 h4 = gfrag(PH, G, 8, 4, l), h5 = gfrag(PH, G, 8, 5, l);
  bf16x8 h6 = gfrag(PH, G, 8, 6, l), h7 = gfrag(PH, G, 8, 7, l);
  acc = MFMA(a2f[4], h4, acc, 0,0,0); acc = MFMA(a2f[5], h5, acc, 0,0,0);
  acc = MFMA(a2f[6], h6, acc, 0,0,0); acc = MFMA(a2f[7], h7, acc, 0,0,0);
  return acc;
}

DEVI void lbar(){
  asm volatile("s_waitcnt lgkmcnt(0)" ::: "memory");
  __builtin_amdgcn_s_barrier();
}

// 128 blocks x 512 threads (8 waves), M=16, 1 block/CU (LDS ~147 KB).
// Lane-local GRU combine (units u0=16w+cc, u1=u0+128). Weights: 16 frags/wave
// in a STATIC per-phase LDS cache (r0 gate + z0-ih), remaining 56 streamed
// L2->VGPR. Cache filled once per phase via global_load_lds.
__global__ __launch_bounds__(512, 1) void vae_main(
    const float* __restrict__ x, const float* __restrict__ eps,
    const float* __restrict__ b_ee,
    const float* __restrict__ bih_f, const float* __restrict__ bhh_f,
    const float* __restrict__ bih_b, const float* __restrict__ bhh_b,
    const float* __restrict__ bih_d, const float* __restrict__ bhh_d,
    const float* __restrict__ b_enc, const float* __restrict__ b_z2h,
    const float* __restrict__ b_h2i, const float* __restrict__ b_ed,
    const float* __restrict__ b_dec,
    const char* __restrict__ ws, float* __restrict__ out)
{
  __shared__ __align__(16) char CW[131072];        // 8 waves x 16 KB weight cache
  __shared__ __align__(16) char A1[2][16 * RB_A1]; // 8704
  __shared__ __align__(16) char A2s[16 * RB_A2];   // 8448
  __shared__ __align__(16) char X0b[2][16 * RB_X]; // 2560
  // HBb aliases CW[0..8448); ST aliases CW+16384 (dead between phases).

  const int tid = threadIdx.x;
  const int l = tid & 63;
  const int w = tid >> 6;       // wave 0..7
  const int cc = l & 15;
  const int g4 = l >> 4;
  const int s0 = blockIdx.x * 16;

  const u16* PIHF = (const u16*)(ws + OFF_IHF);
  const u16* PHHF = (const u16*)(ws + OFF_HHF);
  const u16* PIHB = (const u16*)(ws + OFF_IHB);
  const u16* PIHD = (const u16*)(ws + OFF_IHD);
  const u16* PHHD = (const u16*)(ws + OFF_HHD);
  const u16* PENC = (const u16*)(ws + OFF_ENC);
  const u16* PZ2H = (const u16*)(ws + OFF_Z2H);
  const u16* PH2I = (const u16*)(ws + OFF_H2I);
  const u16* PDEC = (const u16*)(ws + OFF_DEC);
  const u16* PEE  = (const u16*)(ws + OFF_EE);
  const u16* PDE  = (const u16*)(ws + OFF_DE);

  const f32x4 zf = {0.f, 0.f, 0.f, 0.f};
  char* cwb = CW + (size_t)w * 16384;
  char* HBb = CW;
  float* ST = (float*)(CW + 16384);

  // lane-local unit ids and gate biases (encoder set now)
  const int u0 = 16 * w + cc, u1 = u0 + 128;
  float brj[2], bzj[2], bij[2], bhj[2];
  brj[0] = bih_f[u0] + bhh_f[u0];         brj[1] = bih_f[u1] + bhh_f[u1];
  bzj[0] = bih_f[256+u0] + bhh_f[256+u0]; bzj[1] = bih_f[256+u1] + bhh_f[256+u1];
  bij[0] = bih_f[512+u0];                 bij[1] = bih_f[512+u1];
  bhj[0] = bhh_f[512+u0];                 bhj[1] = bhh_f[512+u1];
  const float beer = b_ee[u0];
  const bf16x8 bEE = gfrag(PEE, w, 1, 0, l);

  float hr[8];
  #pragma unroll
  for (int i = 0; i < 8; ++i) hr[i] = 0.f;

  // ---------------- prologue ----------------
  stage_x(x, s0, 0, X0b[0], tid);
  for (int i = tid; i < 16 * RB_A2 / 4; i += 512) ((unsigned*)A2s)[i] = 0u;
  fill_cache(PIHF, PHHF, w, l, cwb);     // enc cache (async)
  __syncthreads();
  {
    bf16x8 a = ldF(X0b[0], cc, g4 * 8, RB_X);
    f32x4 xa = MFMA(a, bEE, zf, 0, 0, 0);
    #pragma unroll
    for (int q = 0; q < 4; ++q)
      stBf(A1[0], g4 * 4 + q, u0, RB_A1, fmaxf(xa[q] + beer, 0.f));
  }
  stage_x(x, s0, 1, X0b[1], tid);
  asm volatile("s_waitcnt vmcnt(0)" ::: "memory");   // cache resident
  __syncthreads();

  // ---------------- encoder: 100 steps ----------------
  for (int t = 0; t < 100; ++t){
    const char* Ab = A1[t & 1];
    bf16x8 a2f[8];
    #pragma unroll
    for (int kt = 0; kt < 8; ++kt) a2f[kt] = ldF(A2s, cc, kt * 32 + g4 * 8, RB_A2);
    lbar();

    // j = 0: r fully cached, z ih-cached
    {
      f32x4 aR = gate_r_cached(cwb, l, cc, g4, Ab, a2f);
      f32x4 aZ = gate_z_cached(cwb, PHHF, w + 16, l, cc, g4, Ab, a2f);
      f32x4 aI = gate_i (PIHF, w + 32, l, cc, g4, Ab);
      f32x4 aH = gate_h (PHHF, w + 32, l, a2f);
      #pragma unroll
      for (int q = 0; q < 4; ++q){
        float r  = sigm(aR[q] + brj[0]);
        float zz = sigm(aZ[q] + bzj[0]);
        float n  = tanh_f(aI[q] + bij[0] + r * (aH[q] + bhj[0]));
        float h  = (1.f - zz) * n + zz * hr[q];
        hr[q] = h;
        stBf(A2s, g4 * 4 + q, u0, RB_A2, h);
      }
    }
    // j = 1: all streamed
    {
      f32x4 aR = gate_rz(PIHF, PHHF, w + 8,  l, cc, g4, Ab, a2f);
      f32x4 aZ = gate_rz(PIHF, PHHF, w + 24, l, cc, g4, Ab, a2f);
      f32x4 aI = gate_i (PIHF, w + 40, l, cc, g4, Ab);
      f32x4 aH = gate_h (PHHF, w + 40, l, a2f);
      #pragma unroll
      for (int q = 0; q < 4; ++q){
        float r  = sigm(aR[q] + brj[1]);
        float zz = sigm(aZ[q] + bzj[1]);
        float n  = tanh_f(aI[q] + bij[1] + r * (aH[q] + bhj[1]));
        float h  = (1.f - zz) * n + zz * hr[4 + q];
        hr[4 + q] = h;
        stBf(A2s, g4 * 4 + q, u1, RB_A2, h);
      }
    }

    if (t < 99){
      bf16x8 a = ldF(X0b[(t + 1) & 1], cc, g4 * 8, RB_X);
      f32x4 xa = MFMA(a, bEE, zf, 0, 0, 0);
      #pragma unroll
      for (int q = 0; q < 4; ++q)
        stBf(A1[(t + 1) & 1], g4 * 4 + q, u0, RB_A1, fmaxf(xa[q] + beer, 0.f));
    }
    if (t < 98) stage_x(x, s0, t + 2, X0b[t & 1], tid);
    lbar();
  }

  // ---------------- backward cell (h0=0), lane-local; HBb clobbers CW ----------------
  {
    bf16x8 b1f[4];
    #pragma unroll
    for (int kt = 0; kt < 4; ++kt) b1f[kt] = ldF(A1[1], cc, kt * 32 + g4 * 8, RB_A1);
    #pragma unroll
    for (int j = 0; j < 2; ++j){
      f32x4 bR = zf, bZ = zf, bI = zf;
      #pragma unroll
      for (int kt = 0; kt < 4; ++kt){
        bR = MFMA(b1f[kt], gfrag(PIHB, w + 8*j,      4, kt, l), bR, 0,0,0);
        bZ = MFMA(b1f[kt], gfrag(PIHB, w + 16 + 8*j, 4, kt, l), bZ, 0,0,0);
        bI = MFMA(b1f[kt], gfrag(PIHB, w + 32 + 8*j, 4, kt, l), bI, 0,0,0);
      }
      const int uj = (j == 0) ? u0 : u1;
      const float brb = bih_b[uj] + bhh_b[uj];
      const float bzb = bih_b[256+uj] + bhh_b[256+uj];
      const float bib = bih_b[512+uj], bhb = bhh_b[512+uj];
      #pragma unroll
      for (int q = 0; q < 4; ++q){
        float r  = sigm(bR[q] + brb);
        float zz = sigm(bZ[q] + bzb);
        float n  = tanh_f(bI[q] + bib + r * bhb);
        stBf(HBb, g4 * 4 + q, uj, RB_A2, (1.f - zz) * n);
      }
    }
  }
  __syncthreads();

  // ---------------- stats = [h_fwd | h_bwd] @ W_enc + b_enc ----------------
  {
    f32x4 sa = zf;
    #pragma unroll
    for (int kt = 0; kt < 8; ++kt)
      sa = MFMA(ldF(A2s, cc, kt * 32 + g4 * 8, RB_A2), gfrag(PENC, w, 16, kt, l), sa, 0, 0, 0);
    #pragma unroll
    for (int kt = 8; kt < 16; ++kt)
      sa = MFMA(ldF(HBb, cc, (kt - 8) * 32 + g4 * 8, RB_A2), gfrag(PENC, w, 16, kt, l), sa, 0, 0, 0);
    const float be = b_enc[16 * w + cc];
    #pragma unroll
    for (int q = 0; q < 4; ++q)
      ST[(g4 * 4 + q) * 132 + 16 * w + cc] = sa[q] + be;
  }
  __syncthreads();

  // ---------------- z; write mu/logvar ----------------
  {
    const int s = tid >> 5, jj = (tid & 31) * 2;
    #pragma unroll
    for (int d = 0; d < 2; ++d){
      const int j = jj + d;
      float mu = ST[s * 132 + j], lv = ST[s * 132 + 64 + j];
      out[6553600u + (size_t)(s0 + s) * 64 + j] = mu;
      out[6684672u + (size_t)(s0 + s) * 64 + j] = lv;
      float zv = mu + __expf(0.5f * lv) * eps[(size_t)(s0 + s) * 64 + j];
      stBf(A1[0], s, j, RB_A1, zv);
    }
  }
  __syncthreads();   // ST fully consumed; CW free for dec cache

  // ---------------- dec cache fill + h_dec0 + dec biases ----------------
  fill_cache(PIHD, PHHD, w, l, cwb);     // async; lands before dec loop
  #pragma unroll
  for (int j = 0; j < 2; ++j){
    const int g = w + 8 * j;
    f32x4 da = zf;
    #pragma unroll
    for (int kt = 0; kt < 2; ++kt)
      da = MFMA(ldF(A1[0], cc, kt * 32 + g4 * 8, RB_A1), gfrag(PZ2H, g, 2, kt, l), da, 0, 0, 0);
    const float bz = b_z2h[(j == 0) ? u0 : u1];
    #pragma unroll
    for (int q = 0; q < 4; ++q){
      float v = fmaxf(da[q] + bz, 0.f);
      hr[j * 4 + q] = v;
      stBf(A2s, g4 * 4 + q, (j == 0) ? u0 : u1, RB_A2, v);
    }
  }
  brj[0] = bih_d[u0] + bhh_d[u0];         brj[1] = bih_d[u1] + bhh_d[u1];
  bzj[0] = bih_d[256+u0] + bhh_d[256+u0]; bzj[1] = bih_d[256+u1] + bhh_d[256+u1];
  bij[0] = bih_d[512+u0];                 bij[1] = bih_d[512+u1];
  bhj[0] = bhh_d[512+u0];                 bhj[1] = bhh_d[512+u1];
  __syncthreads();

  const float bh2ir = (w < 4) ? b_h2i[16 * w + cc] : 0.f;
  const float bder  = (w >= 4) ? ((const float*)(ws + OFF_BDE))[16 * (w - 4) + cc] : 0.f;
  const float bdecr = (w == 2 || w == 3) ? b_dec[16 * (w - 2) + cc] : 0.f;

  // ---------------- hid0 (w<4), cur0 ----------------
  if (w < 4){
    f32x4 ha = zf;
    #pragma unroll
    for (int kt = 0; kt < 8; ++kt)
      ha = MFMA(ldF(A2s, cc, kt * 32 + g4 * 8, RB_A2), gfrag(PH2I, w, 8, kt, l), ha, 0, 0, 0);
    #pragma unroll
    for (int q = 0; q < 4; ++q)
      stBf(A1[0], g4 * 4 + q, 64 + 16 * w + cc, RB_A1, fmaxf(ha[q] + bh2ir, 0.f));
  }
  {
    const int s = tid >> 5, jj = (tid & 31) * 2;
    #pragma unroll
    for (int d = 0; d < 2; ++d)
      stBf(A1[0], s, jj + d, RB_A1, fmaxf(b_ed[jj + d], 0.f));
  }
  asm volatile("s_waitcnt vmcnt(0)" ::: "memory");   // dec cache resident
  __syncthreads();

  // ---------------- decoder: 100 steps ----------------
  for (int t = 0; t < 100; ++t){
    const char* Ab = A1[0];
    bf16x8 a2f[8];
    #pragma unroll
    for (int kt = 0; kt < 8; ++kt) a2f[kt] = ldF(A2s, cc, kt * 32 + g4 * 8, RB_A2);
    lbar();

    {
      f32x4 aR = gate_r_cached(cwb, l, cc, g4, Ab, a2f);
      f32x4 aZ = gate_z_cached(cwb, PHHD, w + 16, l, cc, g4, Ab, a2f);
      f32x4 aI = gate_i (PIHD, w + 32, l, cc, g4, Ab);
      f32x4 aH = gate_h (PHHD, w + 32, l, a2f);
      #pragma unroll
      for (int q = 0; q < 4; ++q){
        float r  = sigm(aR[q] + brj[0]);
        float zz = sigm(aZ[q] + bzj[0]);
        float n  = tanh_f(aI[q] + bij[0] + r * (aH[q] + bhj[0]));
        float h  = (1.f - zz) * n + zz * hr[q];
        hr[q] = h;
        stBf(A2s, g4 * 4 + q, u0, RB_A2, h);
      }
    }
    {
      f32x4 aR = gate_rz(PIHD, PHHD, w + 8,  l, cc, g4, Ab, a2f);
      f32x4 aZ = gate_rz(PIHD, PHHD, w + 24, l, cc, g4, Ab, a2f);
      f32x4 aI = gate_i (PIHD, w + 40, l, cc, g4, Ab);
      f32x4 aH = gate_h (PHHD, w + 40, l, a2f);
      #pragma unroll
      for (int q = 0; q < 4; ++q){
        float r  = sigm(aR[q] + brj[1]);
        float zz = sigm(aZ[q] + bzj[1]);
        float n  = tanh_f(aI[q] + bij[1] + r * (aH[q] + bhj[1]));
        float h  = (1.f - zz) * n + zz * hr[4 + q];
        hr[4 + q] = h;
        stBf(A2s, g4 * 4 + q, u1, RB_A2, h);
      }
    }
    lbar();

    // heads: w0-3 h2i -> A1 hi; w4-7 fused cur (Wde) -> A1 lo; w2-3 x_cur -> out
    {
      bf16x8 af[8];
      #pragma unroll
      for (int kt = 0; kt < 8; ++kt) af[kt] = ldF(A2s, cc, kt * 32 + g4 * 8, RB_A2);
      f32x4 hv = zf;
      if (w < 4){
        #pragma unroll
        for (int kt = 0; kt < 8; ++kt) hv = MFMA(af[kt], gfrag(PH2I, w, 8, kt, l), hv, 0, 0, 0);
        #pragma unroll
        for (int q = 0; q < 4; ++q)
          stBf(A1[0], g4 * 4 + q, 64 + 16 * w + cc, RB_A1, fmaxf(hv[q] + bh2ir, 0.f));
      } else {
        #pragma unroll
        for (int kt = 0; kt < 8; ++kt) hv = MFMA(af[kt], gfrag(PDE, w - 4, 8, kt, l), hv, 0, 0, 0);
        #pragma unroll
        for (int q = 0; q < 4; ++q)
          stBf(A1[0], g4 * 4 + q, 16 * (w - 4) + cc, RB_A1, fmaxf(hv[q] + bder, 0.f));
      }
      if (w == 2 || w == 3){
        f32x4 xc = zf;
        #pragma unroll
        for (int kt = 0; kt < 8; ++kt) xc = MFMA(af[kt], gfrag(PDEC, w - 2, 8, kt, l), xc, 0, 0, 0);
        #pragma unroll
        for (int q = 0; q < 4; ++q)
          out[(size_t)(s0 + g4 * 4 + q) * 3200 + t * 32 + 16 * (w - 2) + cc] = xc[q] + bdecr;
      }
    }
    lbar();
  }
}

extern "C" void kernel_launch(void* const* d_in, const int* in_sizes, int n_in,
                              void* d_out, int out_size, void* d_ws, size_t ws_size,
                              hipStream_t stream)
{
  (void)in_sizes; (void)n_in; (void)out_size;
  if (ws_size < (size_t)WS_TOTAL) return;

  const float* x    = (const float*)d_in[0];
  const float* eps  = (const float*)d_in[1];
  const float* Wee  = (const float*)d_in[2];
  const float* bee  = (const float*)d_in[3];
  const float* Wihf = (const float*)d_in[4];
  const float* Whhf = (const float*)d_in[5];
  const float* bihf = (const float*)d_in[6];
  const float* bhhf = (const float*)d_in[7];
  const float* Wihb = (const float*)d_in[8];
  const float* bihb = (const float*)d_in[10];
  const float* bhhb = (const float*)d_in[11];
  const float* Wenc = (const float*)d_in[12];
  const float* benc = (const float*)d_in[13];
  const float* Wz2h = (const float*)d_in[14];
  const float* bz2h = (const float*)d_in[15];
  const float* Wh2i = (const float*)d_in[16];
  const float* bh2i = (const float*)d_in[17];
  const float* Wihd = (const float*)d_in[18];
  const float* Whhd = (const float*)d_in[19];
  const float* bihd = (const float*)d_in[20];
  const float* bhhd = (const float*)d_in[21];
  const float* Wed  = (const float*)d_in[22];
  const float* bed  = (const float*)d_in[23];
  const float* Wdec = (const float*)d_in[24];
  const float* bdec = (const float*)d_in[25];
  char* ws = (char*)d_ws;

  pack_all<<<3193, 256, 0, stream>>>(Wihf, Whhf, Wihb, Wihd, Whhd, Wenc, Wz2h, Wh2i,
                                     Wdec, Wee, Wed, bed, bdec, ws);
  vae_main<<<128, 512, 0, stream>>>(x, eps, bee, bihf, bhhf, bihb, bhhb, bihd, bhhd,
                                    benc, bz2h, bh2i, bed, bdec, ws, (float*)d_out);
}